// Round 5
// baseline (740.330 us; speedup 1.0000x reference)
//
#include <hip/hip_runtime.h>
#include <math.h>

// ---------------------------------------------------------------------------
// Brain_49374944035335  R5: convs keep A(weights) in dbuf LDS, B(activations)
// gathered DIRECT from global (kills the LDS-read bottleneck: 32 ds_read_b128
// -> 16 per CU per K-step). fc1 -> f16 MFMA with pre-transposed W1 (o-major,
// padded to 640), both passes. h/pre pitch 640.
// ---------------------------------------------------------------------------

#define BN_EPS 1e-5f

typedef _Float16 f16x8 __attribute__((ext_vector_type(8)));
typedef _Float16 f16x4 __attribute__((ext_vector_type(4)));
typedef float    f32x4v __attribute__((ext_vector_type(4)));

constexpr int ilog2c(int x) { return x <= 1 ? 0 : 1 + ilog2c(x >> 1); }

// ---------------- weight pre-transform: OIHW fp32 -> [9][CO*CI] f16 --------
__global__ __launch_bounds__(256)
void wsplit_kernel(const float* __restrict__ w, _Float16* __restrict__ o, int COCI)
{
    const int t = blockIdx.x * 256 + threadIdx.x;
    if (t >= COCI) return;
#pragma unroll
    for (int ph = 0; ph < 9; ++ph)
        o[ph * COCI + t] = (_Float16)w[t * 9 + ph];
}

// conv1 weights: [64][27] fp32 -> [64][32] f16 (pad)
__global__ void wsplit1_kernel(const float* __restrict__ w, _Float16* __restrict__ o)
{
    const int co = threadIdx.x;  // 64
#pragma unroll
    for (int k = 0; k < 32; ++k)
        o[co * 32 + k] = (k < 27) ? (_Float16)w[co * 27 + k] : (_Float16)0.f;
}

// ---------------- W1 transpose: [n][592 k][600 o] f32 -> o-major f16 -------
// Tf [n][640 o][512 k(=80..591)], Tn [n][640 o][96 k(=0..79, pad 0)]
__global__ __launch_bounds__(256)
void w1t_kernel(const float* __restrict__ W1, _Float16* __restrict__ Tf,
                _Float16* __restrict__ Tn)
{
    __shared__ float T[64][65];
    const int n  = blockIdx.z;
    const int o0 = blockIdx.y * 64;   // 10 tiles -> 640
    const int k0 = blockIdx.x * 64;   // 10 tiles -> 640
    const int tid = threadIdx.x;
    const int c  = tid & 63;
    const int r4 = tid >> 6;
    const float* Wn = W1 + (size_t)n * 592 * 600;
#pragma unroll
    for (int rep = 0; rep < 16; ++rep) {
        const int kr = rep * 4 + r4;
        const int k = k0 + kr, o = o0 + c;
        float v = 0.f;
        if (k < 592 && o < 600) v = Wn[k * 600 + o];
        T[kr][c] = v;
    }
    __syncthreads();
#pragma unroll
    for (int rep = 0; rep < 16; ++rep) {
        const int orr = rep * 4 + r4;
        const int o = o0 + orr;
        const int k = k0 + c;
        const float v = T[c][orr];
        if (k >= 80 && k < 592)
            Tf[((size_t)(n * 640 + o)) * 512 + (k - 80)] = (_Float16)v;
        if (k < 96)
            Tn[((size_t)(n * 640 + o)) * 96 + k] = (k < 80) ? (_Float16)v : (_Float16)0.f;
    }
}

__global__ void b1pad_kernel(const float* __restrict__ b1, float* __restrict__ b1p)
{
    const int t = blockIdx.x * 256 + threadIdx.x;
    if (t >= 16 * 640) return;
    const int n = t / 640, o = t - n * 640;
    b1p[t] = (o < 600) ? b1[n * 600 + o] : 0.f;
}

// ---------------- conv1: 3->64 @64x64, MFMA, one K-step --------------------
__global__ __launch_bounds__(256)
void conv1_mfma_kernel(const float* __restrict__ in, const _Float16* __restrict__ w32,
                       _Float16* __restrict__ out, int B)
{
    __shared__ __align__(16) _Float16 As[64 * 32];
    __shared__ __align__(16) _Float16 Bs[128 * 32];

    const int tid  = threadIdx.x;
    const int pix0 = blockIdx.x * 128;
    const int bn   = tid & 127;
    const int bh   = tid >> 7;
    const int gp   = pix0 + bn;
    const int pb   = gp >> 12;
    const int sp   = gp & 4095;
    const int py   = sp >> 6;
    const int px   = sp & 63;
    const float* inb = in + (size_t)pb * 3 * 4096;

    _Float16 vals[16];
    if (bh == 0) {
#pragma unroll
        for (int u = 0; u < 16; ++u) {
            const int k = u;
            const int ci = k / 9, r = k - ci * 9, ky = r / 3, kx = r - ky * 3;
            const int iy = py + ky - 1, ix = px + kx - 1;
            float v = 0.f;
            if ((unsigned)iy < 64u && (unsigned)ix < 64u)
                v = inb[ci * 4096 + iy * 64 + ix];
            vals[u] = (_Float16)v;
        }
    } else {
#pragma unroll
        for (int u = 0; u < 16; ++u) {
            const int k = 16 + u;
            float v = 0.f;
            if (k < 27) {
                const int ci = k / 9, r = k - ci * 9, ky = r / 3, kx = r - ky * 3;
                const int iy = py + ky - 1, ix = px + kx - 1;
                if ((unsigned)iy < 64u && (unsigned)ix < 64u)
                    v = inb[ci * 4096 + iy * 64 + ix];
            }
            vals[u] = (_Float16)v;
        }
    }
    f16x8 b0, b1;
#pragma unroll
    for (int j = 0; j < 8; ++j) { b0[j] = vals[j]; b1[j] = vals[8 + j]; }
    *(f16x8*)&Bs[bn * 32 + (((2 * bh    ) ^ (bn & 3)) << 3)] = b0;
    *(f16x8*)&Bs[bn * 32 + (((2 * bh + 1) ^ (bn & 3)) << 3)] = b1;

    if (tid < 128) {
        const int arow = tid >> 1, ah = tid & 1;
        const f16x8 a0 = *(const f16x8*)(w32 + arow * 32 + ah * 16);
        const f16x8 a1 = *(const f16x8*)(w32 + arow * 32 + ah * 16 + 8);
        *(f16x8*)&As[arow * 32 + (((2 * ah    ) ^ (arow & 3)) << 3)] = a0;
        *(f16x8*)&As[arow * 32 + (((2 * ah + 1) ^ (arow & 3)) << 3)] = a1;
    }
    __syncthreads();

    const int lane = tid & 63, wv = tid >> 6;
    const int q = lane >> 4, lm = lane & 15;
    const int swz = (q ^ (lm & 3)) << 3;

    f16x8 af[4], bf[2];
#pragma unroll
    for (int ti = 0; ti < 4; ++ti)
        af[ti] = *(const f16x8*)&As[(ti * 16 + lm) * 32 + swz];
#pragma unroll
    for (int tj = 0; tj < 2; ++tj)
        bf[tj] = *(const f16x8*)&Bs[(wv * 32 + tj * 16 + lm) * 32 + swz];

    f32x4v acc[4][2];
#pragma unroll
    for (int ti = 0; ti < 4; ++ti)
#pragma unroll
        for (int tj = 0; tj < 2; ++tj)
            acc[ti][tj] = __builtin_amdgcn_mfma_f32_16x16x32_f16(
                af[ti], bf[tj], (f32x4v)0.f, 0, 0, 0);

#pragma unroll
    for (int tj = 0; tj < 2; ++tj) {
        const int gpix = pix0 + wv * 32 + tj * 16 + lm;
#pragma unroll
        for (int ti = 0; ti < 4; ++ti) {
            const int cob = ti * 16 + q * 4;
            f16x4 h4;
#pragma unroll
            for (int r = 0; r < 4; ++r) h4[r] = (_Float16)acc[ti][tj][r];
            *(f16x4*)&out[(size_t)gpix * 64 + cob] = h4;
        }
    }
}

// ---------------- main conv: A in dbuf LDS, B direct from global -----------
// EPI: 0=f16 plain, 1=bias+relu f16, 2=fp32 split-K partial.
template <int CI, int CO, int H, int W, int KSPLIT, int EPI>
__global__ __launch_bounds__(256)
void conv_bd_kernel(const _Float16* __restrict__ in, const _Float16* __restrict__ w9,
                    const float* __restrict__ bias, _Float16* __restrict__ out,
                    float* __restrict__ part, int B)
{
    constexpr int HW   = H * W;
    constexpr int lgHW = ilog2c(HW);
    constexpr int lgW  = ilog2c(W);

    __shared__ __align__(16) _Float16 As[2][128 * 32];

    const int tid  = threadIdx.x;
    const int pix0 = blockIdx.x * 128;
    const int co0  = blockIdx.y * 128;

    const int lane = tid & 63, wv = tid >> 6;
    const int wm = (wv & 1) * 64, wn = (wv >> 1) * 64;
    const int q = lane >> 4, lm = lane & 15;
    const int swz = (q ^ (lm & 3)) << 3;

    const int arow = tid >> 1, ah = tid & 1;
    const int aw0 = ((2 * ah    ) ^ (arow & 3)) << 3;
    const int aw1 = ((2 * ah + 1) ^ (arow & 3)) << 3;
    const _Float16* abase = w9 + ((size_t)(co0 + arow)) * CI + ah * 16;

    // B pixel geometry per tj
    int pbq[4], pyq[4], pxq[4];
#pragma unroll
    for (int tj = 0; tj < 4; ++tj) {
        const int gp = pix0 + wn + tj * 16 + lm;
        pbq[tj] = gp >> lgHW;
        const int sp = gp & (HW - 1);
        pyq[tj] = sp >> lgW;
        pxq[tj] = sp & (W - 1);
    }

    f32x4v acc[4][4];
#pragma unroll
    for (int i = 0; i < 4; ++i)
#pragma unroll
        for (int j = 0; j < 4; ++j) acc[i][j] = (f32x4v)0.f;

    constexpr int CS_TOT = CI / 32;
    constexpr int CS_PER = CS_TOT / KSPLIT;
    const int cs0 = (KSPLIT > 1) ? blockIdx.z * CS_PER : 0;

    int buf = 0;
    for (int ph = 0; ph < 9; ++ph) {
        const int dy = ph / 3 - 1;
        const int dx = ph - (ph / 3) * 3 - 1;
        const _Float16* bb[4];
        f16x8 mskv[4];
#pragma unroll
        for (int tj = 0; tj < 4; ++tj) {
            const int y2 = pyq[tj] + dy, x2 = pxq[tj] + dx;
            const bool valid = ((unsigned)y2 < (unsigned)H) && ((unsigned)x2 < (unsigned)W);
            const int sp2 = valid ? ((y2 << lgW) | x2) : 0;
            bb[tj] = in + ((size_t)((pbq[tj] << lgHW) | sp2)) * CI + q * 8 + cs0 * 32;
            const _Float16 m = valid ? (_Float16)1.f : (_Float16)0.f;
#pragma unroll
            for (int j = 0; j < 8; ++j) mskv[tj][j] = m;
        }
        const _Float16* aph = abase + (size_t)ph * CO * CI + cs0 * 32;

        // stage first A-tile of this phase
        {
            const f16x8 a0 = *(const f16x8*)(aph);
            const f16x8 a1 = *(const f16x8*)(aph + 8);
            __syncthreads();   // all reads of As[buf] from prev phase done
            *(f16x8*)&As[buf][arow * 32 + aw0] = a0;
            *(f16x8*)&As[buf][arow * 32 + aw1] = a1;
        }
        for (int cs = 0; cs < CS_PER; ++cs) {
            f16x8 bfr[4];
#pragma unroll
            for (int tj = 0; tj < 4; ++tj)
                bfr[tj] = *(const f16x8*)(bb[tj] + cs * 32);
            f16x8 aN0, aN1;
            if (cs + 1 < CS_PER) {
                aN0 = *(const f16x8*)(aph + (cs + 1) * 32);
                aN1 = *(const f16x8*)(aph + (cs + 1) * 32 + 8);
            }
            __syncthreads();   // As[buf] visible
            f16x8 afr[4];
#pragma unroll
            for (int ti = 0; ti < 4; ++ti)
                afr[ti] = *(const f16x8*)&As[buf][(wm + ti * 16 + lm) * 32 + swz];
#pragma unroll
            for (int tj = 0; tj < 4; ++tj) bfr[tj] *= mskv[tj];
#pragma unroll
            for (int ti = 0; ti < 4; ++ti)
#pragma unroll
                for (int tj = 0; tj < 4; ++tj)
                    acc[ti][tj] = __builtin_amdgcn_mfma_f32_16x16x32_f16(
                        afr[ti], bfr[tj], acc[ti][tj], 0, 0, 0);
            if (cs + 1 < CS_PER) {
                *(f16x8*)&As[buf ^ 1][arow * 32 + aw0] = aN0;
                *(f16x8*)&As[buf ^ 1][arow * 32 + aw1] = aN1;
                buf ^= 1;
            }
        }
    }

    if (EPI == 2) {
        float* pout = part + (size_t)blockIdx.z * ((size_t)B * HW * CO);
#pragma unroll
        for (int tj = 0; tj < 4; ++tj) {
            const int gpix = pix0 + wn + tj * 16 + lm;
#pragma unroll
            for (int ti = 0; ti < 4; ++ti) {
                const int cob = co0 + wm + ti * 16 + q * 4;
                *(float4*)&pout[(size_t)gpix * CO + cob] =
                    make_float4(acc[ti][tj][0], acc[ti][tj][1],
                                acc[ti][tj][2], acc[ti][tj][3]);
            }
        }
    } else {
#pragma unroll
        for (int tj = 0; tj < 4; ++tj) {
            const int gpix = pix0 + wn + tj * 16 + lm;
#pragma unroll
            for (int ti = 0; ti < 4; ++ti) {
                const int cob = co0 + wm + ti * 16 + q * 4;
                f16x4 h4;
                if (EPI == 1) {
                    const float4 bb4 = *(const float4*)&bias[cob];
                    h4[0] = (_Float16)fmaxf(acc[ti][tj][0] + bb4.x, 0.f);
                    h4[1] = (_Float16)fmaxf(acc[ti][tj][1] + bb4.y, 0.f);
                    h4[2] = (_Float16)fmaxf(acc[ti][tj][2] + bb4.z, 0.f);
                    h4[3] = (_Float16)fmaxf(acc[ti][tj][3] + bb4.w, 0.f);
                } else {
#pragma unroll
                    for (int r = 0; r < 4; ++r) h4[r] = (_Float16)acc[ti][tj][r];
                }
                *(f16x4*)&out[(size_t)gpix * CO + cob] = h4;
            }
        }
    }
}

// ---------------- BN stats over NHWC f16 -----------------------------------
template <int C>
__global__ __launch_bounds__(256)
void bn_stats_nhwc_kernel(const _Float16* __restrict__ in, float* __restrict__ sums,
                          int Ptot)
{
    constexpr int C8 = C / 8;
    constexpr int PS = 256 / C8;
    const int chunk = Ptot / gridDim.x;
    const int c8   = threadIdx.x & (C8 - 1);
    const int poff = threadIdx.x >> ilog2c(C8);
    float s[8], s2[8];
#pragma unroll
    for (int j = 0; j < 8; ++j) { s[j] = 0.f; s2[j] = 0.f; }
    const int p0 = blockIdx.x * chunk;
    for (int p = p0 + poff; p < p0 + chunk; p += PS) {
        const f16x8 v = *(const f16x8*)(in + (size_t)p * C + c8 * 8);
#pragma unroll
        for (int j = 0; j < 8; ++j) {
            const float f = (float)v[j];
            s[j] += f; s2[j] += f * f;
        }
    }
    __shared__ float ls[2 * C];
    for (int i = threadIdx.x; i < 2 * C; i += 256) ls[i] = 0.f;
    __syncthreads();
#pragma unroll
    for (int j = 0; j < 8; ++j) {
        atomicAdd(&ls[c8 * 8 + j], s[j]);
        atomicAdd(&ls[C + c8 * 8 + j], s2[j]);
    }
    __syncthreads();
    for (int i = threadIdx.x; i < 2 * C; i += 256) atomicAdd(&sums[i], ls[i]);
}

template <int C>
__global__ void bn_finalize_kernel(const float* __restrict__ sums,
                                   const float* __restrict__ g,
                                   const float* __restrict__ beta,
                                   float* __restrict__ ss, int Ntot)
{
    const int c = blockIdx.x * 64 + threadIdx.x;
    if (c >= C) return;
    const float inv   = 1.f / (float)Ntot;
    const float mean  = sums[c] * inv;
    const float var   = sums[C + c] * inv - mean * mean;
    const float scale = g[c] * rsqrtf(var + BN_EPS);
    ss[c]     = scale;
    ss[C + c] = beta[c] - mean * scale;
}

// ---------------- maxpool k3 s2 p1, NHWC f16 (opt fused BN+ReLU) -----------
template <int C, int Hin, int Win, bool DO_BN>
__global__ __launch_bounds__(256)
void pool_nhwc_kernel(const _Float16* __restrict__ in, const float* __restrict__ ss,
                      _Float16* __restrict__ out, int B)
{
    constexpr int Ho = Hin / 2, Wo = Win / 2, C8 = C / 8;
    constexpr int lgC8 = ilog2c(C8), lgWo = ilog2c(Wo), lgHo = ilog2c(Ho);
    const int t = blockIdx.x * 256 + threadIdx.x;
    const int total = B * Ho * Wo * C8;
    if (t >= total) return;
    const int c8 = t & (C8 - 1);
    const int r1 = t >> lgC8;
    const int ox = r1 & (Wo - 1);
    const int r2 = r1 >> lgWo;
    const int oy = r2 & (Ho - 1);
    const int b  = r2 >> lgHo;

    float sc[8], sh[8];
    if (DO_BN) {
#pragma unroll
        for (int j = 0; j < 8; ++j) {
            sc[j] = ss[c8 * 8 + j];
            sh[j] = ss[C + c8 * 8 + j];
        }
    }
    float m[8];
#pragma unroll
    for (int j = 0; j < 8; ++j) m[j] = -1e30f;

    const int y0 = max(0, 2 * oy - 1), y1 = min(Hin - 1, 2 * oy + 1);
    const int x0 = max(0, 2 * ox - 1), x1 = min(Win - 1, 2 * ox + 1);
    const _Float16* ib = in + ((size_t)b * Hin * Win) * C + c8 * 8;
    for (int iy = y0; iy <= y1; ++iy)
        for (int ix = x0; ix <= x1; ++ix) {
            const f16x8 v = *(const f16x8*)(ib + (size_t)(iy * Win + ix) * C);
#pragma unroll
            for (int j = 0; j < 8; ++j) {
                float f = (float)v[j];
                if (DO_BN) f = f * sc[j] + sh[j];
                m[j] = fmaxf(m[j], f);
            }
        }
    f16x8 o;
#pragma unroll
    for (int j = 0; j < 8; ++j) {
        float f = m[j];
        if (DO_BN) f = fmaxf(f, 0.f);
        o[j] = (_Float16)f;
    }
    *(f16x8*)&out[((size_t)((b << (lgHo + lgWo)) | (oy << lgWo) | ox)) * C + c8 * 8] = o;
}

// ---------------- split-K partial reduce -> f16 NHWC -----------------------
template <int CO, int Z>
__global__ __launch_bounds__(256)
void sum_bias_relu_nhwc_kernel(const float* __restrict__ part, const float* __restrict__ bias,
                               _Float16* __restrict__ out, int Npix)
{
    const int t = blockIdx.x * 256 + threadIdx.x;
    const int N8 = Npix * CO / 8;
    if (t >= N8) return;
    const size_t i8 = (size_t)t * 8;
    const int c = (int)(i8 & (CO - 1));
    const size_t S = (size_t)Npix * CO;
    float4 x0 = *(const float4*)(part + i8);
    float4 x1 = *(const float4*)(part + i8 + 4);
#pragma unroll
    for (int z = 1; z < Z; ++z) {
        const float4 p0 = *(const float4*)(part + z * S + i8);
        const float4 p1 = *(const float4*)(part + z * S + i8 + 4);
        x0.x += p0.x; x0.y += p0.y; x0.z += p0.z; x0.w += p0.w;
        x1.x += p1.x; x1.y += p1.y; x1.z += p1.z; x1.w += p1.w;
    }
    const float4 b0 = *(const float4*)(bias + c);
    const float4 b1 = *(const float4*)(bias + c + 4);
    f16x8 o;
    o[0] = (_Float16)fmaxf(x0.x + b0.x, 0.f);
    o[1] = (_Float16)fmaxf(x0.y + b0.y, 0.f);
    o[2] = (_Float16)fmaxf(x0.z + b0.z, 0.f);
    o[3] = (_Float16)fmaxf(x0.w + b0.w, 0.f);
    o[4] = (_Float16)fmaxf(x1.x + b1.x, 0.f);
    o[5] = (_Float16)fmaxf(x1.y + b1.y, 0.f);
    o[6] = (_Float16)fmaxf(x1.z + b1.z, 0.f);
    o[7] = (_Float16)fmaxf(x1.w + b1.w, 0.f);
    *(f16x8*)&out[i8] = o;
}

// ---------------- conv7 partials -> X feats (f16) --------------------------
template <int Z>
__global__ __launch_bounds__(256)
void build_xf_kernel(const float* __restrict__ part, const float* __restrict__ bias,
                     _Float16* __restrict__ Xf, int B)
{
    const int t = blockIdx.x * 256 + threadIdx.x;
    if (t >= B * 16 * 128) return;
    const int pix = t >> 7;
    const int c   = (t & 127) * 4;
    const size_t S = (size_t)B * 16 * 512;
    float4 a = *(const float4*)(part + (size_t)pix * 512 + c);
#pragma unroll
    for (int z = 1; z < Z; ++z) {
        const float4 p = *(const float4*)(part + z * S + (size_t)pix * 512 + c);
        a.x += p.x; a.y += p.y; a.z += p.z; a.w += p.w;
    }
    const float4 bb = *(const float4*)(bias + c);
    f16x4 o4;
    o4[0] = (_Float16)fmaxf(a.x + bb.x, 0.f);
    o4[1] = (_Float16)fmaxf(a.y + bb.y, 0.f);
    o4[2] = (_Float16)fmaxf(a.z + bb.z, 0.f);
    o4[3] = (_Float16)fmaxf(a.w + bb.w, 0.f);
    const int b_ = pix >> 4, sp = pix & 15;
    *(f16x4*)&Xf[((size_t)(sp * B + b_)) * 512 + c] = o4;
}

// ---------------- fc1 MFMA: C[o][m] = W1T[o][k] . X[m][k] ------------------
// PASS2: add stored pre instead of b1p; else write pre. h/pre pitch 640.
template <int K, bool PASS2>
__global__ __launch_bounds__(256)
void fc1_mfma_kernel(const _Float16* __restrict__ Xf, const _Float16* __restrict__ W1T,
                     const float* __restrict__ b1p, float* __restrict__ pre,
                     float* __restrict__ h, int B)
{
    __shared__ __align__(16) _Float16 As[2][128 * 32];
    __shared__ __align__(16) _Float16 Bs[2][128 * 32];

    const int tid = threadIdx.x;
    const int o0  = blockIdx.x * 128;
    const int n   = blockIdx.y;

    const int lane = tid & 63, wv = tid >> 6;
    const int wm = (wv & 1) * 64, wn = (wv >> 1) * 64;
    const int q = lane >> 4, lm = lane & 15;
    const int swz = (q ^ (lm & 3)) << 3;

    const int arow = tid >> 1, ah = tid & 1;
    const int aw0 = ((2 * ah    ) ^ (arow & 3)) << 3;
    const int aw1 = ((2 * ah + 1) ^ (arow & 3)) << 3;

    const _Float16* asrc = W1T + ((size_t)(n * 640 + o0 + arow)) * K + ah * 16;
    const _Float16* bsrc = Xf  + ((size_t)(n * 128 + arow)) * K + ah * 16;

    f32x4v acc[4][4];
#pragma unroll
    for (int i = 0; i < 4; ++i)
#pragma unroll
        for (int j = 0; j < 4; ++j) acc[i][j] = (f32x4v)0.f;

    constexpr int S = K / 32;
    {
        const f16x8 a0 = *(const f16x8*)(asrc);
        const f16x8 a1 = *(const f16x8*)(asrc + 8);
        const f16x8 b0 = *(const f16x8*)(bsrc);
        const f16x8 b1 = *(const f16x8*)(bsrc + 8);
        *(f16x8*)&As[0][arow * 32 + aw0] = a0;
        *(f16x8*)&As[0][arow * 32 + aw1] = a1;
        *(f16x8*)&Bs[0][arow * 32 + aw0] = b0;
        *(f16x8*)&Bs[0][arow * 32 + aw1] = b1;
    }
    int buf = 0;
    for (int s = 0; s < S; ++s) {
        f16x8 aN0, aN1, bN0, bN1;
        if (s + 1 < S) {
            aN0 = *(const f16x8*)(asrc + (s + 1) * 32);
            aN1 = *(const f16x8*)(asrc + (s + 1) * 32 + 8);
            bN0 = *(const f16x8*)(bsrc + (s + 1) * 32);
            bN1 = *(const f16x8*)(bsrc + (s + 1) * 32 + 8);
        }
        __syncthreads();
        f16x8 afr[4], bfr[4];
#pragma unroll
        for (int ti = 0; ti < 4; ++ti)
            afr[ti] = *(const f16x8*)&As[buf][(wm + ti * 16 + lm) * 32 + swz];
#pragma unroll
        for (int tj = 0; tj < 4; ++tj)
            bfr[tj] = *(const f16x8*)&Bs[buf][(wn + tj * 16 + lm) * 32 + swz];
#pragma unroll
        for (int ti = 0; ti < 4; ++ti)
#pragma unroll
            for (int tj = 0; tj < 4; ++tj)
                acc[ti][tj] = __builtin_amdgcn_mfma_f32_16x16x32_f16(
                    afr[ti], bfr[tj], acc[ti][tj], 0, 0, 0);
        if (s + 1 < S) {
            *(f16x8*)&As[buf ^ 1][arow * 32 + aw0] = aN0;
            *(f16x8*)&As[buf ^ 1][arow * 32 + aw1] = aN1;
            *(f16x8*)&Bs[buf ^ 1][arow * 32 + aw0] = bN0;
            *(f16x8*)&Bs[buf ^ 1][arow * 32 + aw1] = bN1;
            buf ^= 1;
        }
    }

#pragma unroll
    for (int tj = 0; tj < 4; ++tj) {
        const int m = wn + tj * 16 + lm;
#pragma unroll
        for (int ti = 0; ti < 4; ++ti) {
            const int o = o0 + wm + ti * 16 + q * 4;
            const size_t oi = ((size_t)(n * 128 + m)) * 640 + o;
            float4 base;
            if (PASS2) base = *(const float4*)&pre[oi];
            else       base = *(const float4*)&b1p[n * 640 + o];
            float4 v = make_float4(acc[ti][tj][0] + base.x, acc[ti][tj][1] + base.y,
                                   acc[ti][tj][2] + base.z, acc[ti][tj][3] + base.w);
            if (!PASS2) *(float4*)&pre[oi] = v;
            *(float4*)&h[oi] = make_float4(tanhf(v.x), tanhf(v.y), tanhf(v.z), tanhf(v.w));
        }
    }
}

// ---------------- colons fc2 + softmax (h pitch 640) -----------------------
__global__ __launch_bounds__(128)
void colon_fc2_kernel(const float* __restrict__ h, const float* __restrict__ W2,
                      const float* __restrict__ b2, float* __restrict__ preds, int B)
{
    const int n = blockIdx.x;
    __shared__ float W2s[6000];
    __shared__ float b2s[10];
    for (int i = threadIdx.x; i < 6000; i += 128) W2s[i] = W2[n * 6000 + i];
    if (threadIdx.x < 10) b2s[threadIdx.x] = b2[n * 10 + threadIdx.x];
    __syncthreads();

    for (int b = threadIdx.x; b < B; b += 128) {
        float l[10];
#pragma unroll
        for (int c = 0; c < 10; ++c) l[c] = b2s[c];
        const float* hp = h + ((size_t)(n * B + b)) * 640;
        for (int k = 0; k < 600; k += 4) {
            const float4 hv = *reinterpret_cast<const float4*>(&hp[k]);
            const float hh[4] = {hv.x, hv.y, hv.z, hv.w};
#pragma unroll
            for (int u = 0; u < 4; ++u)
#pragma unroll
                for (int c = 0; c < 10; ++c)
                    l[c] += hh[u] * W2s[(k + u) * 10 + c];
        }
        float mx = l[0];
#pragma unroll
        for (int c = 1; c < 10; ++c) mx = fmaxf(mx, l[c]);
        float s = 0.f;
#pragma unroll
        for (int c = 0; c < 10; ++c) { l[c] = expf(l[c] - mx); s += l[c]; }
        const float inv = 1.f / s;
        float* pp = preds + ((size_t)(n * B + b)) * 10;
#pragma unroll
        for (int c = 0; c < 10; ++c) pp[c] = l[c] * inv;
    }
}

// ---------------- neighbor gather -> Xn f16 [16][B][96] --------------------
__global__ __launch_bounds__(256)
void fill_neigh_kernel(const float* __restrict__ preds1, _Float16* __restrict__ Xn, int B)
{
    const int t = blockIdx.x * 256 + threadIdx.x;
    if (t >= 16 * B * 96) return;
    const int col = t % 96;
    const int b   = (t / 96) % B;
    const int n   = t / (96 * B);

    float v = 0.f;
    if (col < 80) {
        const int j = col / 10, c = col - j * 10;
        int lst[8];
        int cnt = 0;
        const int w = 4, sz = 16, i = n;
        if (i - w >= 0)                                lst[cnt++] = i - w;
        if (i % w != 0)                                lst[cnt++] = i - 1;
        if ((i + 1) % w != 0)                          lst[cnt++] = i + 1;
        if (i + w < sz)                                lst[cnt++] = i + w;
        if (i - w - 1 >= 0 && i % w != 0)              lst[cnt++] = i - w - 1;
        if (i - w + 1 >= 0 && (i + 1) % w != 0)        lst[cnt++] = i - w + 1;
        if (i + w - 1 < sz && i % w != 0)              lst[cnt++] = i + w - 1;
        if (i + w + 1 < sz && (i + 1) % w != 0)        lst[cnt++] = i + w + 1;
        if (j < cnt) v = preds1[((size_t)(lst[j] * B + b)) * 10 + c];
    }
    Xn[t] = (_Float16)v;
}

// ---------------- final ----------------------------------------------------
__global__ __launch_bounds__(256)
void final_out_kernel(const float* __restrict__ preds2, float* __restrict__ out0, int B)
{
    const int t = blockIdx.x * 256 + threadIdx.x;
    if (t >= B * 10) return;
    const int b = t / 10, c = t % 10;
    float s = 0.f;
#pragma unroll
    for (int n = 0; n < 16; ++n)
        s += preds2[((size_t)(n * B + b)) * 10 + c];
    const float m = s * (1.f / 16.f);
    out0[t] = m * m;
}

// ---------------------------------------------------------------------------
extern "C" void kernel_launch(void* const* d_in, const int* in_sizes, int n_in,
                              void* d_out, int out_size, void* d_ws, size_t ws_size,
                              hipStream_t stream)
{
    const float* x    = (const float*)d_in[0];
    const float* cw1  = (const float*)d_in[1];
    const float* bn1g = (const float*)d_in[3];
    const float* bn1b = (const float*)d_in[4];
    const float* cw2  = (const float*)d_in[5];
    const float* bn2g = (const float*)d_in[7];
    const float* bn2b = (const float*)d_in[8];
    const float* cw3  = (const float*)d_in[9];
    const float* cb3  = (const float*)d_in[10];
    const float* cw4  = (const float*)d_in[11];
    const float* cb4  = (const float*)d_in[12];
    const float* cw5  = (const float*)d_in[13];
    const float* cb5  = (const float*)d_in[14];
    const float* cw6  = (const float*)d_in[15];
    const float* cb6  = (const float*)d_in[16];
    const float* cw7  = (const float*)d_in[17];
    const float* cb7  = (const float*)d_in[18];
    const float* W1   = (const float*)d_in[19];
    const float* b1   = (const float*)d_in[20];
    const float* W2   = (const float*)d_in[21];
    const float* b2   = (const float*)d_in[22];

    const int B = in_sizes[0] / (3 * 64 * 64);   // 128

    // ---- workspace layout (f32 offsets) ----
    float* ws = (float*)d_ws;
    float*     P    = ws;                                  // 8,388,608 f32
    _Float16*  A    = (_Float16*)(ws + 8388608);           // 33.6M f16
    _Float16*  Bb   = (_Float16*)(ws + 25165824);          // 16.8M f16
    _Float16*  wreg = (_Float16*)(ws + 33554432);          // conv weights f16
    _Float16*  W1Tf = (_Float16*)(ws + 36984832);          // 16*640*512 f16
    _Float16*  W1Tn = (_Float16*)(ws + 39606272);          // 16*640*96  f16
    _Float16*  Xf16 = (_Float16*)(ws + 40097792);          // 16*128*512 f16
    _Float16*  Xn16 = (_Float16*)(ws + 40622080);          // 16*128*96  f16
    float*     b1p  = ws + 40720384;                       // 16*640
    float*     preb = ws + 40730624;                       // 16*128*640
    float*     hb   = ws + 42041344;                       // 16*128*640
    float*     small= ws + 43352064;
    float* sums1  = small;          // 128
    float* sums2  = small + 256;    // 256
    float* ss1    = small + 1024;   // 128
    float* ss2    = small + 1536;   // 256
    float* preds1 = small + 2048;   // 16*B*10

    _Float16* w1f  = wreg;                  // 2048
    _Float16* w9c2 = wreg + 2048;
    _Float16* w9c3 = w9c2 + 73728;
    _Float16* w9c4 = w9c3 + 294912;
    _Float16* w9c5 = w9c4 + 589824;
    _Float16* w9c6 = w9c5 + 1179648;
    _Float16* w9c7 = w9c6 + 2359296;

    float* out0   = (float*)d_out;
    float* preds2 = (float*)d_out + (size_t)B * 10;

    hipMemsetAsync(small, 0, 512 * sizeof(float), stream);

    // ---- weight pre-transforms ----
    wsplit1_kernel<<<1, 64, 0, stream>>>(cw1, w1f);
    wsplit_kernel<<<(128 * 64  + 255) / 256, 256, 0, stream>>>(cw2, w9c2, 128 * 64);
    wsplit_kernel<<<(256 * 128 + 255) / 256, 256, 0, stream>>>(cw3, w9c3, 256 * 128);
    wsplit_kernel<<<(256 * 256 + 255) / 256, 256, 0, stream>>>(cw4, w9c4, 256 * 256);
    wsplit_kernel<<<(512 * 256 + 255) / 256, 256, 0, stream>>>(cw5, w9c5, 512 * 256);
    wsplit_kernel<<<(512 * 512 + 255) / 256, 256, 0, stream>>>(cw6, w9c6, 512 * 512);
    wsplit_kernel<<<(512 * 512 + 255) / 256, 256, 0, stream>>>(cw7, w9c7, 512 * 512);
    w1t_kernel<<<dim3(10, 10, 16), 256, 0, stream>>>(W1, W1Tf, W1Tn);
    b1pad_kernel<<<(16 * 640 + 255) / 256, 256, 0, stream>>>(b1, b1p);

    // ---- backbone (acts f16 NHWC) ----
    conv1_mfma_kernel<<<B * 4096 / 128, 256, 0, stream>>>(x, w1f, A, B);
    bn_stats_nhwc_kernel<64><<<512, 256, 0, stream>>>(A, sums1, B * 4096);
    bn_finalize_kernel<64><<<1, 64, 0, stream>>>(sums1, bn1g, bn1b, ss1, B * 4096);
    pool_nhwc_kernel<64, 64, 64, true>
        <<<(B * 1024 * 8 + 255) / 256, 256, 0, stream>>>(A, ss1, Bb, B);

    conv_bd_kernel<64, 128, 32, 32, 1, 0>
        <<<dim3(B * 1024 / 128, 1), 256, 0, stream>>>(Bb, w9c2, nullptr, A, nullptr, B);
    bn_stats_nhwc_kernel<128><<<256, 256, 0, stream>>>(A, sums2, B * 1024);
    bn_finalize_kernel<128><<<2, 64, 0, stream>>>(sums2, bn2g, bn2b, ss2, B * 1024);
    pool_nhwc_kernel<128, 32, 32, true>
        <<<(B * 256 * 16 + 255) / 256, 256, 0, stream>>>(A, ss2, Bb, B);

    conv_bd_kernel<128, 256, 16, 16, 1, 1>
        <<<dim3(B * 256 / 128, 2), 256, 0, stream>>>(Bb, w9c3, cb3, A, nullptr, B);
    conv_bd_kernel<256, 256, 16, 16, 1, 1>
        <<<dim3(B * 256 / 128, 2), 256, 0, stream>>>(A, w9c4, cb4, Bb, nullptr, B);
    pool_nhwc_kernel<256, 16, 16, false>
        <<<(B * 64 * 32 + 255) / 256, 256, 0, stream>>>(Bb, nullptr, A, B);

    conv_bd_kernel<256, 512, 8, 8, 2, 2>
        <<<dim3(B * 64 / 128, 4, 2), 256, 0, stream>>>(A, w9c5, nullptr, nullptr, P, B);
    sum_bias_relu_nhwc_kernel<512, 2>
        <<<(B * 64 * 512 / 8 + 255) / 256, 256, 0, stream>>>(P, cb5, Bb, B * 64);

    conv_bd_kernel<512, 512, 8, 8, 2, 2>
        <<<dim3(B * 64 / 128, 4, 2), 256, 0, stream>>>(Bb, w9c6, nullptr, nullptr, P, B);
    sum_bias_relu_nhwc_kernel<512, 2>
        <<<(B * 64 * 512 / 8 + 255) / 256, 256, 0, stream>>>(P, cb6, A, B * 64);
    pool_nhwc_kernel<512, 8, 8, false>
        <<<(B * 16 * 64 + 255) / 256, 256, 0, stream>>>(A, nullptr, Bb, B);

    conv_bd_kernel<512, 512, 4, 4, 8, 2>
        <<<dim3(B * 16 / 128, 4, 8), 256, 0, stream>>>(Bb, w9c7, nullptr, nullptr, P, B);

    // ---- colons ----
    build_xf_kernel<8><<<(B * 16 * 128 + 255) / 256, 256, 0, stream>>>(P, cb7, Xf16, B);

    fc1_mfma_kernel<512, false>
        <<<dim3(5, 16), 256, 0, stream>>>(Xf16, W1Tf, b1p, preb, hb, B);
    colon_fc2_kernel<<<16, 128, 0, stream>>>(hb, W2, b2, preds1, B);

    fill_neigh_kernel<<<(16 * B * 96 + 255) / 256, 256, 0, stream>>>(preds1, Xn16, B);
    fc1_mfma_kernel<96, true>
        <<<dim3(5, 16), 256, 0, stream>>>(Xn16, W1Tn, b1p, preb, hb, B);
    colon_fc2_kernel<<<16, 128, 0, stream>>>(hb, W2, b2, preds2, B);

    final_out_kernel<<<(B * 10 + 255) / 256, 256, 0, stream>>>(preds2, out0, B);
}

// Round 6
// 732.916 us; speedup vs baseline: 1.0101x; 1.0101x over previous
//
#include <hip/hip_runtime.h>
#include <math.h>

// ---------------------------------------------------------------------------
// Brain_49374944035335  R6: conv K-loop software-pipelined (register prefetch
// distance 1 for B-frags and A-tile), LDS-only barrier (s_waitcnt lgkmcnt(0);
// s_barrier) so global loads stay in flight across the barrier. OOB taps read
// a zeroed scratch page (no mask multiplies). Rest as R5.
// ---------------------------------------------------------------------------

#define BN_EPS 1e-5f

typedef _Float16 f16x8 __attribute__((ext_vector_type(8)));
typedef _Float16 f16x4 __attribute__((ext_vector_type(4)));
typedef float    f32x4v __attribute__((ext_vector_type(4)));

constexpr int ilog2c(int x) { return x <= 1 ? 0 : 1 + ilog2c(x >> 1); }

__device__ __forceinline__ void lds_barrier() {
    asm volatile("s_waitcnt lgkmcnt(0)\n\ts_barrier" ::: "memory");
}

// ---------------- weight pre-transform: OIHW fp32 -> [9][CO*CI] f16 --------
__global__ __launch_bounds__(256)
void wsplit_kernel(const float* __restrict__ w, _Float16* __restrict__ o, int COCI)
{
    const int t = blockIdx.x * 256 + threadIdx.x;
    if (t >= COCI) return;
#pragma unroll
    for (int ph = 0; ph < 9; ++ph)
        o[ph * COCI + t] = (_Float16)w[t * 9 + ph];
}

// conv1 weights: [64][27] fp32 -> [64][32] f16 (pad)
__global__ void wsplit1_kernel(const float* __restrict__ w, _Float16* __restrict__ o)
{
    const int co = threadIdx.x;  // 64
#pragma unroll
    for (int k = 0; k < 32; ++k)
        o[co * 32 + k] = (k < 27) ? (_Float16)w[co * 27 + k] : (_Float16)0.f;
}

// ---------------- W1 transpose: [n][592 k][600 o] f32 -> o-major f16 -------
__global__ __launch_bounds__(256)
void w1t_kernel(const float* __restrict__ W1, _Float16* __restrict__ Tf,
                _Float16* __restrict__ Tn)
{
    __shared__ float T[64][65];
    const int n  = blockIdx.z;
    const int o0 = blockIdx.y * 64;
    const int k0 = blockIdx.x * 64;
    const int tid = threadIdx.x;
    const int c  = tid & 63;
    const int r4 = tid >> 6;
    const float* Wn = W1 + (size_t)n * 592 * 600;
#pragma unroll
    for (int rep = 0; rep < 16; ++rep) {
        const int kr = rep * 4 + r4;
        const int k = k0 + kr, o = o0 + c;
        float v = 0.f;
        if (k < 592 && o < 600) v = Wn[k * 600 + o];
        T[kr][c] = v;
    }
    __syncthreads();
#pragma unroll
    for (int rep = 0; rep < 16; ++rep) {
        const int orr = rep * 4 + r4;
        const int o = o0 + orr;
        const int k = k0 + c;
        const float v = T[c][orr];
        if (k >= 80 && k < 592)
            Tf[((size_t)(n * 640 + o)) * 512 + (k - 80)] = (_Float16)v;
        if (k < 96)
            Tn[((size_t)(n * 640 + o)) * 96 + k] = (k < 80) ? (_Float16)v : (_Float16)0.f;
    }
}

__global__ void b1pad_kernel(const float* __restrict__ b1, float* __restrict__ b1p)
{
    const int t = blockIdx.x * 256 + threadIdx.x;
    if (t >= 16 * 640) return;
    const int n = t / 640, o = t - n * 640;
    b1p[t] = (o < 600) ? b1[n * 600 + o] : 0.f;
}

// ---------------- conv1: 3->64 @64x64, MFMA, one K-step --------------------
__global__ __launch_bounds__(256)
void conv1_mfma_kernel(const float* __restrict__ in, const _Float16* __restrict__ w32,
                       _Float16* __restrict__ out, int B)
{
    __shared__ __align__(16) _Float16 As[64 * 32];
    __shared__ __align__(16) _Float16 Bs[128 * 32];

    const int tid  = threadIdx.x;
    const int pix0 = blockIdx.x * 128;
    const int bn   = tid & 127;
    const int bh   = tid >> 7;
    const int gp   = pix0 + bn;
    const int pb   = gp >> 12;
    const int sp   = gp & 4095;
    const int py   = sp >> 6;
    const int px   = sp & 63;
    const float* inb = in + (size_t)pb * 3 * 4096;

    _Float16 vals[16];
    if (bh == 0) {
#pragma unroll
        for (int u = 0; u < 16; ++u) {
            const int k = u;
            const int ci = k / 9, r = k - ci * 9, ky = r / 3, kx = r - ky * 3;
            const int iy = py + ky - 1, ix = px + kx - 1;
            float v = 0.f;
            if ((unsigned)iy < 64u && (unsigned)ix < 64u)
                v = inb[ci * 4096 + iy * 64 + ix];
            vals[u] = (_Float16)v;
        }
    } else {
#pragma unroll
        for (int u = 0; u < 16; ++u) {
            const int k = 16 + u;
            float v = 0.f;
            if (k < 27) {
                const int ci = k / 9, r = k - ci * 9, ky = r / 3, kx = r - ky * 3;
                const int iy = py + ky - 1, ix = px + kx - 1;
                if ((unsigned)iy < 64u && (unsigned)ix < 64u)
                    v = inb[ci * 4096 + iy * 64 + ix];
            }
            vals[u] = (_Float16)v;
        }
    }
    f16x8 b0, b1;
#pragma unroll
    for (int j = 0; j < 8; ++j) { b0[j] = vals[j]; b1[j] = vals[8 + j]; }
    *(f16x8*)&Bs[bn * 32 + (((2 * bh    ) ^ (bn & 3)) << 3)] = b0;
    *(f16x8*)&Bs[bn * 32 + (((2 * bh + 1) ^ (bn & 3)) << 3)] = b1;

    if (tid < 128) {
        const int arow = tid >> 1, ah = tid & 1;
        const f16x8 a0 = *(const f16x8*)(w32 + arow * 32 + ah * 16);
        const f16x8 a1 = *(const f16x8*)(w32 + arow * 32 + ah * 16 + 8);
        *(f16x8*)&As[arow * 32 + (((2 * ah    ) ^ (arow & 3)) << 3)] = a0;
        *(f16x8*)&As[arow * 32 + (((2 * ah + 1) ^ (arow & 3)) << 3)] = a1;
    }
    __syncthreads();

    const int lane = tid & 63, wv = tid >> 6;
    const int q = lane >> 4, lm = lane & 15;
    const int swz = (q ^ (lm & 3)) << 3;

    f16x8 af[4], bf[2];
#pragma unroll
    for (int ti = 0; ti < 4; ++ti)
        af[ti] = *(const f16x8*)&As[(ti * 16 + lm) * 32 + swz];
#pragma unroll
    for (int tj = 0; tj < 2; ++tj)
        bf[tj] = *(const f16x8*)&Bs[(wv * 32 + tj * 16 + lm) * 32 + swz];

    f32x4v acc[4][2];
#pragma unroll
    for (int ti = 0; ti < 4; ++ti)
#pragma unroll
        for (int tj = 0; tj < 2; ++tj)
            acc[ti][tj] = __builtin_amdgcn_mfma_f32_16x16x32_f16(
                af[ti], bf[tj], (f32x4v)0.f, 0, 0, 0);

#pragma unroll
    for (int tj = 0; tj < 2; ++tj) {
        const int gpix = pix0 + wv * 32 + tj * 16 + lm;
#pragma unroll
        for (int ti = 0; ti < 4; ++ti) {
            const int cob = ti * 16 + q * 4;
            f16x4 h4;
#pragma unroll
            for (int r = 0; r < 4; ++r) h4[r] = (_Float16)acc[ti][tj][r];
            *(f16x4*)&out[(size_t)gpix * 64 + cob] = h4;
        }
    }
}

// ---------------- pipelined conv: A dbuf LDS, B global w/ distance-1 prefetch
// EPI: 0=f16 plain, 1=bias+relu f16, 2=fp32 split-K partial.
template <int CI, int CO, int H, int W, int KSPLIT, int EPI>
__global__ __launch_bounds__(256)
void conv_pl_kernel(const _Float16* __restrict__ in, const _Float16* __restrict__ w9,
                    const float* __restrict__ bias, _Float16* __restrict__ out,
                    float* __restrict__ part, const _Float16* __restrict__ zbuf, int B)
{
    constexpr int HW   = H * W;
    constexpr int lgHW = ilog2c(HW);
    constexpr int lgW  = ilog2c(W);

    __shared__ __align__(16) _Float16 As[2][128 * 32];

    const int tid  = threadIdx.x;
    const int pix0 = blockIdx.x * 128;
    const int co0  = blockIdx.y * 128;

    const int lane = tid & 63, wv = tid >> 6;
    const int wm = (wv & 1) * 64, wn = (wv >> 1) * 64;
    const int q = lane >> 4, lm = lane & 15;
    const int swz = (q ^ (lm & 3)) << 3;

    const int arow = tid >> 1, ah = tid & 1;
    const int aw0 = ((2 * ah    ) ^ (arow & 3)) << 3;
    const int aw1 = ((2 * ah + 1) ^ (arow & 3)) << 3;
    const _Float16* abase = w9 + ((size_t)(co0 + arow)) * CI + ah * 16;

    // pixel geometry per tj
    int pbq[4], pyq[4], pxq[4];
#pragma unroll
    for (int tj = 0; tj < 4; ++tj) {
        const int gp = pix0 + wn + tj * 16 + lm;
        pbq[tj] = gp >> lgHW;
        const int sp = gp & (HW - 1);
        pyq[tj] = sp >> lgW;
        pxq[tj] = sp & (W - 1);
    }

    constexpr int CS_TOT = CI / 32;
    constexpr int CS_PER = CS_TOT / KSPLIT;
    constexpr int NIT    = 9 * CS_PER;
    const int cs0 = (KSPLIT > 1) ? blockIdx.z * CS_PER : 0;

    const _Float16* bp[4];
    auto setB = [&](int phx) {
        const int dy = phx / 3 - 1;
        const int dx = phx - (phx / 3) * 3 - 1;
#pragma unroll
        for (int tj = 0; tj < 4; ++tj) {
            const int y2 = pyq[tj] + dy, x2 = pxq[tj] + dx;
            const bool valid = ((unsigned)y2 < (unsigned)H) && ((unsigned)x2 < (unsigned)W);
            const int sp2 = (y2 << lgW) | x2;
            bp[tj] = valid ? (in + ((size_t)((pbq[tj] << lgHW) | sp2)) * CI + q * 8)
                           : (zbuf + q * 8);
        }
    };

    f32x4v acc[4][4];
#pragma unroll
    for (int i = 0; i < 4; ++i)
#pragma unroll
        for (int j = 0; j < 4; ++j) acc[i][j] = (f32x4v)0.f;

    // ---- prologue: stage (ph=0, cs=0) ----
    setB(0);
    f16x8 bcur[4];
#pragma unroll
    for (int tj = 0; tj < 4; ++tj)
        bcur[tj] = *(const f16x8*)(bp[tj] + (size_t)cs0 * 32);
    {
        const f16x8 a0 = *(const f16x8*)(abase + (size_t)cs0 * 32);
        const f16x8 a1 = *(const f16x8*)(abase + (size_t)cs0 * 32 + 8);
        *(f16x8*)&As[0][arow * 32 + aw0] = a0;
        *(f16x8*)&As[0][arow * 32 + aw1] = a1;
    }

    int buf = 0, ph = 0, cs = 0;
    for (int it = 0; it < NIT; ++it) {
        // ---- prefetch step it+1 (registers; stays in flight across barrier)
        int phn = ph, csn = cs + 1;
        const bool adv = (csn == CS_PER);
        if (adv) { csn = 0; phn = ph + 1; }
        const bool havenext = (it + 1 < NIT);
        f16x8 bnext[4], aN0, aN1;
        if (havenext) {
            if (adv) setB(phn);
#pragma unroll
            for (int tj = 0; tj < 4; ++tj)
                bnext[tj] = *(const f16x8*)(bp[tj] + (size_t)(cs0 + csn) * 32);
            const _Float16* aphn = abase + (size_t)phn * CO * CI;
            aN0 = *(const f16x8*)(aphn + (size_t)(cs0 + csn) * 32);
            aN1 = *(const f16x8*)(aphn + (size_t)(cs0 + csn) * 32 + 8);
        }

        lds_barrier();   // LDS-only drain: A-tile[buf] writes visible

        f16x8 afr[4];
#pragma unroll
        for (int ti = 0; ti < 4; ++ti)
            afr[ti] = *(const f16x8*)&As[buf][(wm + ti * 16 + lm) * 32 + swz];
#pragma unroll
        for (int ti = 0; ti < 4; ++ti)
#pragma unroll
            for (int tj = 0; tj < 4; ++tj)
                acc[ti][tj] = __builtin_amdgcn_mfma_f32_16x16x32_f16(
                    afr[ti], bcur[tj], acc[ti][tj], 0, 0, 0);

        if (havenext) {
            *(f16x8*)&As[buf ^ 1][arow * 32 + aw0] = aN0;
            *(f16x8*)&As[buf ^ 1][arow * 32 + aw1] = aN1;
            buf ^= 1;
#pragma unroll
            for (int tj = 0; tj < 4; ++tj) bcur[tj] = bnext[tj];
            ph = phn; cs = csn;
        }
    }

    if (EPI == 2) {
        float* pout = part + (size_t)blockIdx.z * ((size_t)B * HW * CO);
#pragma unroll
        for (int tj = 0; tj < 4; ++tj) {
            const int gpix = pix0 + wn + tj * 16 + lm;
#pragma unroll
            for (int ti = 0; ti < 4; ++ti) {
                const int cob = co0 + wm + ti * 16 + q * 4;
                *(float4*)&pout[(size_t)gpix * CO + cob] =
                    make_float4(acc[ti][tj][0], acc[ti][tj][1],
                                acc[ti][tj][2], acc[ti][tj][3]);
            }
        }
    } else {
#pragma unroll
        for (int tj = 0; tj < 4; ++tj) {
            const int gpix = pix0 + wn + tj * 16 + lm;
#pragma unroll
            for (int ti = 0; ti < 4; ++ti) {
                const int cob = co0 + wm + ti * 16 + q * 4;
                f16x4 h4;
                if (EPI == 1) {
                    const float4 bb4 = *(const float4*)&bias[cob];
                    h4[0] = (_Float16)fmaxf(acc[ti][tj][0] + bb4.x, 0.f);
                    h4[1] = (_Float16)fmaxf(acc[ti][tj][1] + bb4.y, 0.f);
                    h4[2] = (_Float16)fmaxf(acc[ti][tj][2] + bb4.z, 0.f);
                    h4[3] = (_Float16)fmaxf(acc[ti][tj][3] + bb4.w, 0.f);
                } else {
#pragma unroll
                    for (int r = 0; r < 4; ++r) h4[r] = (_Float16)acc[ti][tj][r];
                }
                *(f16x4*)&out[(size_t)gpix * CO + cob] = h4;
            }
        }
    }
}

// ---------------- BN stats over NHWC f16 -----------------------------------
template <int C>
__global__ __launch_bounds__(256)
void bn_stats_nhwc_kernel(const _Float16* __restrict__ in, float* __restrict__ sums,
                          int Ptot)
{
    constexpr int C8 = C / 8;
    constexpr int PS = 256 / C8;
    const int chunk = Ptot / gridDim.x;
    const int c8   = threadIdx.x & (C8 - 1);
    const int poff = threadIdx.x >> ilog2c(C8);
    float s[8], s2[8];
#pragma unroll
    for (int j = 0; j < 8; ++j) { s[j] = 0.f; s2[j] = 0.f; }
    const int p0 = blockIdx.x * chunk;
    for (int p = p0 + poff; p < p0 + chunk; p += PS) {
        const f16x8 v = *(const f16x8*)(in + (size_t)p * C + c8 * 8);
#pragma unroll
        for (int j = 0; j < 8; ++j) {
            const float f = (float)v[j];
            s[j] += f; s2[j] += f * f;
        }
    }
    __shared__ float ls[2 * C];
    for (int i = threadIdx.x; i < 2 * C; i += 256) ls[i] = 0.f;
    __syncthreads();
#pragma unroll
    for (int j = 0; j < 8; ++j) {
        atomicAdd(&ls[c8 * 8 + j], s[j]);
        atomicAdd(&ls[C + c8 * 8 + j], s2[j]);
    }
    __syncthreads();
    for (int i = threadIdx.x; i < 2 * C; i += 256) atomicAdd(&sums[i], ls[i]);
}

template <int C>
__global__ void bn_finalize_kernel(const float* __restrict__ sums,
                                   const float* __restrict__ g,
                                   const float* __restrict__ beta,
                                   float* __restrict__ ss, int Ntot)
{
    const int c = blockIdx.x * 64 + threadIdx.x;
    if (c >= C) return;
    const float inv   = 1.f / (float)Ntot;
    const float mean  = sums[c] * inv;
    const float var   = sums[C + c] * inv - mean * mean;
    const float scale = g[c] * rsqrtf(var + BN_EPS);
    ss[c]     = scale;
    ss[C + c] = beta[c] - mean * scale;
}

// ---------------- maxpool k3 s2 p1, NHWC f16 (opt fused BN+ReLU) -----------
template <int C, int Hin, int Win, bool DO_BN>
__global__ __launch_bounds__(256)
void pool_nhwc_kernel(const _Float16* __restrict__ in, const float* __restrict__ ss,
                      _Float16* __restrict__ out, int B)
{
    constexpr int Ho = Hin / 2, Wo = Win / 2, C8 = C / 8;
    constexpr int lgC8 = ilog2c(C8), lgWo = ilog2c(Wo), lgHo = ilog2c(Ho);
    const int t = blockIdx.x * 256 + threadIdx.x;
    const int total = B * Ho * Wo * C8;
    if (t >= total) return;
    const int c8 = t & (C8 - 1);
    const int r1 = t >> lgC8;
    const int ox = r1 & (Wo - 1);
    const int r2 = r1 >> lgWo;
    const int oy = r2 & (Ho - 1);
    const int b  = r2 >> lgHo;

    float sc[8], sh[8];
    if (DO_BN) {
#pragma unroll
        for (int j = 0; j < 8; ++j) {
            sc[j] = ss[c8 * 8 + j];
            sh[j] = ss[C + c8 * 8 + j];
        }
    }
    float m[8];
#pragma unroll
    for (int j = 0; j < 8; ++j) m[j] = -1e30f;

    const int y0 = max(0, 2 * oy - 1), y1 = min(Hin - 1, 2 * oy + 1);
    const int x0 = max(0, 2 * ox - 1), x1 = min(Win - 1, 2 * ox + 1);
    const _Float16* ib = in + ((size_t)b * Hin * Win) * C + c8 * 8;
    for (int iy = y0; iy <= y1; ++iy)
        for (int ix = x0; ix <= x1; ++ix) {
            const f16x8 v = *(const f16x8*)(ib + (size_t)(iy * Win + ix) * C);
#pragma unroll
            for (int j = 0; j < 8; ++j) {
                float f = (float)v[j];
                if (DO_BN) f = f * sc[j] + sh[j];
                m[j] = fmaxf(m[j], f);
            }
        }
    f16x8 o;
#pragma unroll
    for (int j = 0; j < 8; ++j) {
        float f = m[j];
        if (DO_BN) f = fmaxf(f, 0.f);
        o[j] = (_Float16)f;
    }
    *(f16x8*)&out[((size_t)((b << (lgHo + lgWo)) | (oy << lgWo) | ox)) * C + c8 * 8] = o;
}

// ---------------- split-K partial reduce -> f16 NHWC -----------------------
template <int CO, int Z>
__global__ __launch_bounds__(256)
void sum_bias_relu_nhwc_kernel(const float* __restrict__ part, const float* __restrict__ bias,
                               _Float16* __restrict__ out, int Npix)
{
    const int t = blockIdx.x * 256 + threadIdx.x;
    const int N8 = Npix * CO / 8;
    if (t >= N8) return;
    const size_t i8 = (size_t)t * 8;
    const int c = (int)(i8 & (CO - 1));
    const size_t S = (size_t)Npix * CO;
    float4 x0 = *(const float4*)(part + i8);
    float4 x1 = *(const float4*)(part + i8 + 4);
#pragma unroll
    for (int z = 1; z < Z; ++z) {
        const float4 p0 = *(const float4*)(part + z * S + i8);
        const float4 p1 = *(const float4*)(part + z * S + i8 + 4);
        x0.x += p0.x; x0.y += p0.y; x0.z += p0.z; x0.w += p0.w;
        x1.x += p1.x; x1.y += p1.y; x1.z += p1.z; x1.w += p1.w;
    }
    const float4 b0 = *(const float4*)(bias + c);
    const float4 b1 = *(const float4*)(bias + c + 4);
    f16x8 o;
    o[0] = (_Float16)fmaxf(x0.x + b0.x, 0.f);
    o[1] = (_Float16)fmaxf(x0.y + b0.y, 0.f);
    o[2] = (_Float16)fmaxf(x0.z + b0.z, 0.f);
    o[3] = (_Float16)fmaxf(x0.w + b0.w, 0.f);
    o[4] = (_Float16)fmaxf(x1.x + b1.x, 0.f);
    o[5] = (_Float16)fmaxf(x1.y + b1.y, 0.f);
    o[6] = (_Float16)fmaxf(x1.z + b1.z, 0.f);
    o[7] = (_Float16)fmaxf(x1.w + b1.w, 0.f);
    *(f16x8*)&out[i8] = o;
}

// ---------------- conv7 partials -> X feats (f16) --------------------------
template <int Z>
__global__ __launch_bounds__(256)
void build_xf_kernel(const float* __restrict__ part, const float* __restrict__ bias,
                     _Float16* __restrict__ Xf, int B)
{
    const int t = blockIdx.x * 256 + threadIdx.x;
    if (t >= B * 16 * 128) return;
    const int pix = t >> 7;
    const int c   = (t & 127) * 4;
    const size_t S = (size_t)B * 16 * 512;
    float4 a = *(const float4*)(part + (size_t)pix * 512 + c);
#pragma unroll
    for (int z = 1; z < Z; ++z) {
        const float4 p = *(const float4*)(part + z * S + (size_t)pix * 512 + c);
        a.x += p.x; a.y += p.y; a.z += p.z; a.w += p.w;
    }
    const float4 bb = *(const float4*)(bias + c);
    f16x4 o4;
    o4[0] = (_Float16)fmaxf(a.x + bb.x, 0.f);
    o4[1] = (_Float16)fmaxf(a.y + bb.y, 0.f);
    o4[2] = (_Float16)fmaxf(a.z + bb.z, 0.f);
    o4[3] = (_Float16)fmaxf(a.w + bb.w, 0.f);
    const int b_ = pix >> 4, sp = pix & 15;
    *(f16x4*)&Xf[((size_t)(sp * B + b_)) * 512 + c] = o4;
}

// ---------------- fc1 MFMA: C[o][m] = W1T[o][k] . X[m][k] ------------------
template <int K, bool PASS2>
__global__ __launch_bounds__(256)
void fc1_mfma_kernel(const _Float16* __restrict__ Xf, const _Float16* __restrict__ W1T,
                     const float* __restrict__ b1p, float* __restrict__ pre,
                     float* __restrict__ h, int B)
{
    __shared__ __align__(16) _Float16 As[2][128 * 32];
    __shared__ __align__(16) _Float16 Bs[2][128 * 32];

    const int tid = threadIdx.x;
    const int o0  = blockIdx.x * 128;
    const int n   = blockIdx.y;

    const int lane = tid & 63, wv = tid >> 6;
    const int wm = (wv & 1) * 64, wn = (wv >> 1) * 64;
    const int q = lane >> 4, lm = lane & 15;
    const int swz = (q ^ (lm & 3)) << 3;

    const int arow = tid >> 1, ah = tid & 1;
    const int aw0 = ((2 * ah    ) ^ (arow & 3)) << 3;
    const int aw1 = ((2 * ah + 1) ^ (arow & 3)) << 3;

    const _Float16* asrc = W1T + ((size_t)(n * 640 + o0 + arow)) * K + ah * 16;
    const _Float16* bsrc = Xf  + ((size_t)(n * 128 + arow)) * K + ah * 16;

    f32x4v acc[4][4];
#pragma unroll
    for (int i = 0; i < 4; ++i)
#pragma unroll
        for (int j = 0; j < 4; ++j) acc[i][j] = (f32x4v)0.f;

    constexpr int S = K / 32;
    {
        const f16x8 a0 = *(const f16x8*)(asrc);
        const f16x8 a1 = *(const f16x8*)(asrc + 8);
        const f16x8 b0 = *(const f16x8*)(bsrc);
        const f16x8 b1 = *(const f16x8*)(bsrc + 8);
        *(f16x8*)&As[0][arow * 32 + aw0] = a0;
        *(f16x8*)&As[0][arow * 32 + aw1] = a1;
        *(f16x8*)&Bs[0][arow * 32 + aw0] = b0;
        *(f16x8*)&Bs[0][arow * 32 + aw1] = b1;
    }
    int buf = 0;
    for (int s = 0; s < S; ++s) {
        f16x8 aN0, aN1, bN0, bN1;
        if (s + 1 < S) {
            aN0 = *(const f16x8*)(asrc + (s + 1) * 32);
            aN1 = *(const f16x8*)(asrc + (s + 1) * 32 + 8);
            bN0 = *(const f16x8*)(bsrc + (s + 1) * 32);
            bN1 = *(const f16x8*)(bsrc + (s + 1) * 32 + 8);
        }
        lds_barrier();
        f16x8 afr[4], bfr[4];
#pragma unroll
        for (int ti = 0; ti < 4; ++ti)
            afr[ti] = *(const f16x8*)&As[buf][(wm + ti * 16 + lm) * 32 + swz];
#pragma unroll
        for (int tj = 0; tj < 4; ++tj)
            bfr[tj] = *(const f16x8*)&Bs[buf][(wn + tj * 16 + lm) * 32 + swz];
#pragma unroll
        for (int ti = 0; ti < 4; ++ti)
#pragma unroll
            for (int tj = 0; tj < 4; ++tj)
                acc[ti][tj] = __builtin_amdgcn_mfma_f32_16x16x32_f16(
                    afr[ti], bfr[tj], acc[ti][tj], 0, 0, 0);
        if (s + 1 < S) {
            *(f16x8*)&As[buf ^ 1][arow * 32 + aw0] = aN0;
            *(f16x8*)&As[buf ^ 1][arow * 32 + aw1] = aN1;
            *(f16x8*)&Bs[buf ^ 1][arow * 32 + aw0] = bN0;
            *(f16x8*)&Bs[buf ^ 1][arow * 32 + aw1] = bN1;
            buf ^= 1;
        }
    }

#pragma unroll
    for (int tj = 0; tj < 4; ++tj) {
        const int m = wn + tj * 16 + lm;
#pragma unroll
        for (int ti = 0; ti < 4; ++ti) {
            const int o = o0 + wm + ti * 16 + q * 4;
            const size_t oi = ((size_t)(n * 128 + m)) * 640 + o;
            float4 base;
            if (PASS2) base = *(const float4*)&pre[oi];
            else       base = *(const float4*)&b1p[n * 640 + o];
            float4 v = make_float4(acc[ti][tj][0] + base.x, acc[ti][tj][1] + base.y,
                                   acc[ti][tj][2] + base.z, acc[ti][tj][3] + base.w);
            if (!PASS2) *(float4*)&pre[oi] = v;
            *(float4*)&h[oi] = make_float4(tanhf(v.x), tanhf(v.y), tanhf(v.z), tanhf(v.w));
        }
    }
}

// ---------------- colons fc2 + softmax (h pitch 640) -----------------------
__global__ __launch_bounds__(128)
void colon_fc2_kernel(const float* __restrict__ h, const float* __restrict__ W2,
                      const float* __restrict__ b2, float* __restrict__ preds, int B)
{
    const int n = blockIdx.x;
    __shared__ float W2s[6000];
    __shared__ float b2s[10];
    for (int i = threadIdx.x; i < 6000; i += 128) W2s[i] = W2[n * 6000 + i];
    if (threadIdx.x < 10) b2s[threadIdx.x] = b2[n * 10 + threadIdx.x];
    __syncthreads();

    for (int b = threadIdx.x; b < B; b += 128) {
        float l[10];
#pragma unroll
        for (int c = 0; c < 10; ++c) l[c] = b2s[c];
        const float* hp = h + ((size_t)(n * B + b)) * 640;
        for (int k = 0; k < 600; k += 4) {
            const float4 hv = *reinterpret_cast<const float4*>(&hp[k]);
            const float hh[4] = {hv.x, hv.y, hv.z, hv.w};
#pragma unroll
            for (int u = 0; u < 4; ++u)
#pragma unroll
                for (int c = 0; c < 10; ++c)
                    l[c] += hh[u] * W2s[(k + u) * 10 + c];
        }
        float mx = l[0];
#pragma unroll
        for (int c = 1; c < 10; ++c) mx = fmaxf(mx, l[c]);
        float s = 0.f;
#pragma unroll
        for (int c = 0; c < 10; ++c) { l[c] = expf(l[c] - mx); s += l[c]; }
        const float inv = 1.f / s;
        float* pp = preds + ((size_t)(n * B + b)) * 10;
#pragma unroll
        for (int c = 0; c < 10; ++c) pp[c] = l[c] * inv;
    }
}

// ---------------- neighbor gather -> Xn f16 [16][B][96] --------------------
__global__ __launch_bounds__(256)
void fill_neigh_kernel(const float* __restrict__ preds1, _Float16* __restrict__ Xn, int B)
{
    const int t = blockIdx.x * 256 + threadIdx.x;
    if (t >= 16 * B * 96) return;
    const int col = t % 96;
    const int b   = (t / 96) % B;
    const int n   = t / (96 * B);

    float v = 0.f;
    if (col < 80) {
        const int j = col / 10, c = col - j * 10;
        int lst[8];
        int cnt = 0;
        const int w = 4, sz = 16, i = n;
        if (i - w >= 0)                                lst[cnt++] = i - w;
        if (i % w != 0)                                lst[cnt++] = i - 1;
        if ((i + 1) % w != 0)                          lst[cnt++] = i + 1;
        if (i + w < sz)                                lst[cnt++] = i + w;
        if (i - w - 1 >= 0 && i % w != 0)              lst[cnt++] = i - w - 1;
        if (i - w + 1 >= 0 && (i + 1) % w != 0)        lst[cnt++] = i - w + 1;
        if (i + w - 1 < sz && i % w != 0)              lst[cnt++] = i + w - 1;
        if (i + w + 1 < sz && (i + 1) % w != 0)        lst[cnt++] = i + w + 1;
        if (j < cnt) v = preds1[((size_t)(lst[j] * B + b)) * 10 + c];
    }
    Xn[t] = (_Float16)v;
}

// ---------------- final ----------------------------------------------------
__global__ __launch_bounds__(256)
void final_out_kernel(const float* __restrict__ preds2, float* __restrict__ out0, int B)
{
    const int t = blockIdx.x * 256 + threadIdx.x;
    if (t >= B * 10) return;
    const int b = t / 10, c = t % 10;
    float s = 0.f;
#pragma unroll
    for (int n = 0; n < 16; ++n)
        s += preds2[((size_t)(n * B + b)) * 10 + c];
    const float m = s * (1.f / 16.f);
    out0[t] = m * m;
}

// ---------------------------------------------------------------------------
extern "C" void kernel_launch(void* const* d_in, const int* in_sizes, int n_in,
                              void* d_out, int out_size, void* d_ws, size_t ws_size,
                              hipStream_t stream)
{
    const float* x    = (const float*)d_in[0];
    const float* cw1  = (const float*)d_in[1];
    const float* bn1g = (const float*)d_in[3];
    const float* bn1b = (const float*)d_in[4];
    const float* cw2  = (const float*)d_in[5];
    const float* bn2g = (const float*)d_in[7];
    const float* bn2b = (const float*)d_in[8];
    const float* cw3  = (const float*)d_in[9];
    const float* cb3  = (const float*)d_in[10];
    const float* cw4  = (const float*)d_in[11];
    const float* cb4  = (const float*)d_in[12];
    const float* cw5  = (const float*)d_in[13];
    const float* cb5  = (const float*)d_in[14];
    const float* cw6  = (const float*)d_in[15];
    const float* cb6  = (const float*)d_in[16];
    const float* cw7  = (const float*)d_in[17];
    const float* cb7  = (const float*)d_in[18];
    const float* W1   = (const float*)d_in[19];
    const float* b1   = (const float*)d_in[20];
    const float* W2   = (const float*)d_in[21];
    const float* b2   = (const float*)d_in[22];

    const int B = in_sizes[0] / (3 * 64 * 64);   // 128

    // ---- workspace layout (f32 offsets) ----
    float* ws = (float*)d_ws;
    float*     P    = ws;                                  // 8,388,608 f32
    _Float16*  A    = (_Float16*)(ws + 8388608);           // 33.6M f16
    _Float16*  Bb   = (_Float16*)(ws + 25165824);          // 16.8M f16
    _Float16*  wreg = (_Float16*)(ws + 33554432);          // conv weights f16
    _Float16*  W1Tf = (_Float16*)(ws + 36984832);          // 16*640*512 f16
    _Float16*  W1Tn = (_Float16*)(ws + 39606272);          // 16*640*96  f16
    _Float16*  Xf16 = (_Float16*)(ws + 40097792);          // 16*128*512 f16
    _Float16*  Xn16 = (_Float16*)(ws + 40622080);          // 16*128*96  f16
    float*     b1p  = ws + 40720384;                       // 16*640
    float*     preb = ws + 40730624;                       // 16*128*640
    float*     hb   = ws + 42041344;                       // 16*128*640
    float*     small= ws + 43352064;
    float* sums1  = small;          // 128
    float* sums2  = small + 256;    // 256
    float* ss1    = small + 1024;   // 128
    float* ss2    = small + 1536;   // 256
    float* preds1 = small + 2048;   // 16*B*10
    _Float16* zbuf = (_Float16*)(small + 32768);           // 4 KB zero page

    _Float16* w1f  = wreg;                  // 2048
    _Float16* w9c2 = wreg + 2048;
    _Float16* w9c3 = w9c2 + 73728;
    _Float16* w9c4 = w9c3 + 294912;
    _Float16* w9c5 = w9c4 + 589824;
    _Float16* w9c6 = w9c5 + 1179648;
    _Float16* w9c7 = w9c6 + 2359296;

    float* out0   = (float*)d_out;
    float* preds2 = (float*)d_out + (size_t)B * 10;

    hipMemsetAsync(small, 0, 512 * sizeof(float), stream);
    hipMemsetAsync(zbuf, 0, 4096, stream);

    // ---- weight pre-transforms ----
    wsplit1_kernel<<<1, 64, 0, stream>>>(cw1, w1f);
    wsplit_kernel<<<(128 * 64  + 255) / 256, 256, 0, stream>>>(cw2, w9c2, 128 * 64);
    wsplit_kernel<<<(256 * 128 + 255) / 256, 256, 0, stream>>>(cw3, w9c3, 256 * 128);
    wsplit_kernel<<<(256 * 256 + 255) / 256, 256, 0, stream>>>(cw4, w9c4, 256 * 256);
    wsplit_kernel<<<(512 * 256 + 255) / 256, 256, 0, stream>>>(cw5, w9c5, 512 * 256);
    wsplit_kernel<<<(512 * 512 + 255) / 256, 256, 0, stream>>>(cw6, w9c6, 512 * 512);
    wsplit_kernel<<<(512 * 512 + 255) / 256, 256, 0, stream>>>(cw7, w9c7, 512 * 512);
    w1t_kernel<<<dim3(10, 10, 16), 256, 0, stream>>>(W1, W1Tf, W1Tn);
    b1pad_kernel<<<(16 * 640 + 255) / 256, 256, 0, stream>>>(b1, b1p);

    // ---- backbone (acts f16 NHWC) ----
    conv1_mfma_kernel<<<B * 4096 / 128, 256, 0, stream>>>(x, w1f, A, B);
    bn_stats_nhwc_kernel<64><<<512, 256, 0, stream>>>(A, sums1, B * 4096);
    bn_finalize_kernel<64><<<1, 64, 0, stream>>>(sums1, bn1g, bn1b, ss1, B * 4096);
    pool_nhwc_kernel<64, 64, 64, true>
        <<<(B * 1024 * 8 + 255) / 256, 256, 0, stream>>>(A, ss1, Bb, B);

    conv_pl_kernel<64, 128, 32, 32, 1, 0>
        <<<dim3(B * 1024 / 128, 1), 256, 0, stream>>>(Bb, w9c2, nullptr, A, nullptr, zbuf, B);
    bn_stats_nhwc_kernel<128><<<256, 256, 0, stream>>>(A, sums2, B * 1024);
    bn_finalize_kernel<128><<<2, 64, 0, stream>>>(sums2, bn2g, bn2b, ss2, B * 1024);
    pool_nhwc_kernel<128, 32, 32, true>
        <<<(B * 256 * 16 + 255) / 256, 256, 0, stream>>>(A, ss2, Bb, B);

    conv_pl_kernel<128, 256, 16, 16, 1, 1>
        <<<dim3(B * 256 / 128, 2), 256, 0, stream>>>(Bb, w9c3, cb3, A, nullptr, zbuf, B);
    conv_pl_kernel<256, 256, 16, 16, 1, 1>
        <<<dim3(B * 256 / 128, 2), 256, 0, stream>>>(A, w9c4, cb4, Bb, nullptr, zbuf, B);
    pool_nhwc_kernel<256, 16, 16, false>
        <<<(B * 64 * 32 + 255) / 256, 256, 0, stream>>>(Bb, nullptr, A, B);

    conv_pl_kernel<256, 512, 8, 8, 2, 2>
        <<<dim3(B * 64 / 128, 4, 2), 256, 0, stream>>>(A, w9c5, nullptr, nullptr, P, zbuf, B);
    sum_bias_relu_nhwc_kernel<512, 2>
        <<<(B * 64 * 512 / 8 + 255) / 256, 256, 0, stream>>>(P, cb5, Bb, B * 64);

    conv_pl_kernel<512, 512, 8, 8, 2, 2>
        <<<dim3(B * 64 / 128, 4, 2), 256, 0, stream>>>(Bb, w9c6, nullptr, nullptr, P, zbuf, B);
    sum_bias_relu_nhwc_kernel<512, 2>
        <<<(B * 64 * 512 / 8 + 255) / 256, 256, 0, stream>>>(P, cb6, A, B * 64);
    pool_nhwc_kernel<512, 8, 8, false>
        <<<(B * 16 * 64 + 255) / 256, 256, 0, stream>>>(A, nullptr, Bb, B);

    conv_pl_kernel<512, 512, 4, 4, 8, 2>
        <<<dim3(B * 16 / 128, 4, 8), 256, 0, stream>>>(Bb, w9c7, nullptr, nullptr, P, zbuf, B);

    // ---- colons ----
    build_xf_kernel<8><<<(B * 16 * 128 + 255) / 256, 256, 0, stream>>>(P, cb7, Xf16, B);

    fc1_mfma_kernel<512, false>
        <<<dim3(5, 16), 256, 0, stream>>>(Xf16, W1Tf, b1p, preb, hb, B);
    colon_fc2_kernel<<<16, 128, 0, stream>>>(hb, W2, b2, preds1, B);

    fill_neigh_kernel<<<(16 * B * 96 + 255) / 256, 256, 0, stream>>>(preds1, Xn16, B);
    fc1_mfma_kernel<96, true>
        <<<dim3(5, 16), 256, 0, stream>>>(Xn16, W1Tn, b1p, preb, hb, B);
    colon_fc2_kernel<<<16, 128, 0, stream>>>(hb, W2, b2, preds2, B);

    final_out_kernel<<<(B * 10 + 255) / 256, 256, 0, stream>>>(preds2, out0, B);
}

// Round 7
// 633.894 us; speedup vs baseline: 1.1679x; 1.1562x over previous
//
#include <hip/hip_runtime.h>
#include <math.h>

// ---------------------------------------------------------------------------
// Brain_49374944035335  R7: conv = both-operands-in-LDS (best measured, R4)
// + distance-2 register prefetch + triple-buffered LDS + lgkm-only barrier
// (global loads stay in flight across 2 barriers). Loop unrolled x6 so queue
// indices fold to constants. Merged weight-prep into one kernel.
// ---------------------------------------------------------------------------

#define BN_EPS 1e-5f

typedef _Float16 f16x8 __attribute__((ext_vector_type(8)));
typedef _Float16 f16x4 __attribute__((ext_vector_type(4)));
typedef float    f32x4v __attribute__((ext_vector_type(4)));

constexpr int ilog2c(int x) { return x <= 1 ? 0 : 1 + ilog2c(x >> 1); }

__device__ __forceinline__ void lds_barrier() {
    asm volatile("s_waitcnt lgkmcnt(0)\n\ts_barrier" ::: "memory");
}

// ---------------- merged weight prep ---------------------------------------
// layer 0: conv1 [64][27]->[64][32] f16 pad. layers 1..6: conv2..7
// OIHW fp32 -> [9][CO*CI] f16 at fixed offsets in wreg.
__global__ __launch_bounds__(256)
void wprep_kernel(const float* __restrict__ cw1, const float* __restrict__ cw2,
                  const float* __restrict__ cw3, const float* __restrict__ cw4,
                  const float* __restrict__ cw5, const float* __restrict__ cw6,
                  const float* __restrict__ cw7, _Float16* __restrict__ wreg)
{
    const int layer = blockIdx.y;
    const int t = blockIdx.x * 256 + threadIdx.x;
    if (layer == 0) {
        if (t < 64) {
#pragma unroll
            for (int k = 0; k < 32; ++k)
                wreg[t * 32 + k] = (k < 27) ? (_Float16)cw1[t * 27 + k] : (_Float16)0.f;
        }
        return;
    }
    const float* src = nullptr;
    _Float16* dst = nullptr;
    int n = 0;
    switch (layer) {
        case 1: src = cw2; dst = wreg + 2048;    n = 8192;   break;
        case 2: src = cw3; dst = wreg + 75776;   n = 32768;  break;
        case 3: src = cw4; dst = wreg + 370688;  n = 65536;  break;
        case 4: src = cw5; dst = wreg + 960512;  n = 131072; break;
        case 5: src = cw6; dst = wreg + 2140160; n = 262144; break;
        case 6: src = cw7; dst = wreg + 4499456; n = 262144; break;
    }
    if (t >= n) return;
#pragma unroll
    for (int ph = 0; ph < 9; ++ph)
        dst[ph * n + t] = (_Float16)src[t * 9 + ph];
}

// ---------------- W1 transpose: [n][592 k][600 o] f32 -> o-major f16 -------
__global__ __launch_bounds__(256)
void w1t_kernel(const float* __restrict__ W1, _Float16* __restrict__ Tf,
                _Float16* __restrict__ Tn)
{
    __shared__ float T[64][65];
    const int n  = blockIdx.z;
    const int o0 = blockIdx.y * 64;
    const int k0 = blockIdx.x * 64;
    const int tid = threadIdx.x;
    const int c  = tid & 63;
    const int r4 = tid >> 6;
    const float* Wn = W1 + (size_t)n * 592 * 600;
#pragma unroll
    for (int rep = 0; rep < 16; ++rep) {
        const int kr = rep * 4 + r4;
        const int k = k0 + kr, o = o0 + c;
        float v = 0.f;
        if (k < 592 && o < 600) v = Wn[k * 600 + o];
        T[kr][c] = v;
    }
    __syncthreads();
#pragma unroll
    for (int rep = 0; rep < 16; ++rep) {
        const int orr = rep * 4 + r4;
        const int o = o0 + orr;
        const int k = k0 + c;
        const float v = T[c][orr];
        if (k >= 80 && k < 592)
            Tf[((size_t)(n * 640 + o)) * 512 + (k - 80)] = (_Float16)v;
        if (k < 96)
            Tn[((size_t)(n * 640 + o)) * 96 + k] = (k < 80) ? (_Float16)v : (_Float16)0.f;
    }
}

__global__ void b1pad_kernel(const float* __restrict__ b1, float* __restrict__ b1p)
{
    const int t = blockIdx.x * 256 + threadIdx.x;
    if (t >= 16 * 640) return;
    const int n = t / 640, o = t - n * 640;
    b1p[t] = (o < 600) ? b1[n * 600 + o] : 0.f;
}

// ---------------- conv1: 3->64 @64x64, MFMA, one K-step --------------------
__global__ __launch_bounds__(256)
void conv1_mfma_kernel(const float* __restrict__ in, const _Float16* __restrict__ w32,
                       _Float16* __restrict__ out, int B)
{
    __shared__ __align__(16) _Float16 As[64 * 32];
    __shared__ __align__(16) _Float16 Bs[128 * 32];

    const int tid  = threadIdx.x;
    const int pix0 = blockIdx.x * 128;
    const int bn   = tid & 127;
    const int bh   = tid >> 7;
    const int gp   = pix0 + bn;
    const int pb   = gp >> 12;
    const int sp   = gp & 4095;
    const int py   = sp >> 6;
    const int px   = sp & 63;
    const float* inb = in + (size_t)pb * 3 * 4096;

    _Float16 vals[16];
    if (bh == 0) {
#pragma unroll
        for (int u = 0; u < 16; ++u) {
            const int k = u;
            const int ci = k / 9, r = k - ci * 9, ky = r / 3, kx = r - ky * 3;
            const int iy = py + ky - 1, ix = px + kx - 1;
            float v = 0.f;
            if ((unsigned)iy < 64u && (unsigned)ix < 64u)
                v = inb[ci * 4096 + iy * 64 + ix];
            vals[u] = (_Float16)v;
        }
    } else {
#pragma unroll
        for (int u = 0; u < 16; ++u) {
            const int k = 16 + u;
            float v = 0.f;
            if (k < 27) {
                const int ci = k / 9, r = k - ci * 9, ky = r / 3, kx = r - ky * 3;
                const int iy = py + ky - 1, ix = px + kx - 1;
                if ((unsigned)iy < 64u && (unsigned)ix < 64u)
                    v = inb[ci * 4096 + iy * 64 + ix];
            }
            vals[u] = (_Float16)v;
        }
    }
    f16x8 b0, b1;
#pragma unroll
    for (int j = 0; j < 8; ++j) { b0[j] = vals[j]; b1[j] = vals[8 + j]; }
    *(f16x8*)&Bs[bn * 32 + (((2 * bh    ) ^ (bn & 3)) << 3)] = b0;
    *(f16x8*)&Bs[bn * 32 + (((2 * bh + 1) ^ (bn & 3)) << 3)] = b1;

    if (tid < 128) {
        const int arow = tid >> 1, ah = tid & 1;
        const f16x8 a0 = *(const f16x8*)(w32 + arow * 32 + ah * 16);
        const f16x8 a1 = *(const f16x8*)(w32 + arow * 32 + ah * 16 + 8);
        *(f16x8*)&As[arow * 32 + (((2 * ah    ) ^ (arow & 3)) << 3)] = a0;
        *(f16x8*)&As[arow * 32 + (((2 * ah + 1) ^ (arow & 3)) << 3)] = a1;
    }
    __syncthreads();

    const int lane = tid & 63, wv = tid >> 6;
    const int q = lane >> 4, lm = lane & 15;
    const int swz = (q ^ (lm & 3)) << 3;

    f16x8 af[4], bf[2];
#pragma unroll
    for (int ti = 0; ti < 4; ++ti)
        af[ti] = *(const f16x8*)&As[(ti * 16 + lm) * 32 + swz];
#pragma unroll
    for (int tj = 0; tj < 2; ++tj)
        bf[tj] = *(const f16x8*)&Bs[(wv * 32 + tj * 16 + lm) * 32 + swz];

    f32x4v acc[4][2];
#pragma unroll
    for (int ti = 0; ti < 4; ++ti)
#pragma unroll
        for (int tj = 0; tj < 2; ++tj)
            acc[ti][tj] = __builtin_amdgcn_mfma_f32_16x16x32_f16(
                af[ti], bf[tj], (f32x4v)0.f, 0, 0, 0);

#pragma unroll
    for (int tj = 0; tj < 2; ++tj) {
        const int gpix = pix0 + wv * 32 + tj * 16 + lm;
#pragma unroll
        for (int ti = 0; ti < 4; ++ti) {
            const int cob = ti * 16 + q * 4;
            f16x4 h4;
#pragma unroll
            for (int r = 0; r < 4; ++r) h4[r] = (_Float16)acc[ti][tj][r];
            *(f16x4*)&out[(size_t)gpix * 64 + cob] = h4;
        }
    }
}

// ---------------- conv: both LDS, dist-2 prefetch, triple-buffer -----------
// EPI: 0=f16 plain, 1=bias+relu f16, 2=fp32 split-K partial.
template <int CI, int CO, int H, int W, int KSPLIT, int EPI>
__global__ __launch_bounds__(256)
void conv_p2_kernel(const _Float16* __restrict__ in, const _Float16* __restrict__ w9,
                    const float* __restrict__ bias, _Float16* __restrict__ out,
                    float* __restrict__ part, const _Float16* __restrict__ zbuf, int B)
{
    constexpr int HW   = H * W;
    constexpr int lgHW = ilog2c(HW);
    constexpr int lgW  = ilog2c(W);

    __shared__ __align__(16) _Float16 As[3][128 * 32];
    __shared__ __align__(16) _Float16 Bs[3][128 * 32];

    const int tid  = threadIdx.x;
    const int pix0 = blockIdx.x * 128;
    const int co0  = blockIdx.y * 128;

    const int lane = tid & 63, wv = tid >> 6;
    const int wm = (wv & 1) * 64, wn = (wv >> 1) * 64;
    const int q = lane >> 4, lm = lane & 15;
    const int swz = (q ^ (lm & 3)) << 3;

    // A staging: thread -> (weight row, 16-f16 half)
    const int arow = tid >> 1, ah = tid & 1;
    const int aw0 = ((2 * ah    ) ^ (arow & 3)) << 3;
    const int aw1 = ((2 * ah + 1) ^ (arow & 3)) << 3;
    const _Float16* abase = w9 + ((size_t)(co0 + arow)) * CI + ah * 16;

    // B staging: thread -> (pixel, ci-half)
    const int bn = tid & 127, bh = tid >> 7;
    const int gp = pix0 + bn;
    const int pb = gp >> lgHW;
    const int spx = gp & (HW - 1);
    const int py = spx >> lgW, px = spx & (W - 1);
    const int bw0 = ((2 * bh    ) ^ (bn & 3)) << 3;
    const int bw1 = ((2 * bh + 1) ^ (bn & 3)) << 3;

    constexpr int CS_TOT = CI / 32;
    constexpr int CS_PER = CS_TOT / KSPLIT;
    constexpr int NIT    = 9 * CS_PER;          // 18/36/72 (all % 6 == 0)
    const int cs0 = (KSPLIT > 1) ? blockIdx.z * CS_PER : 0;

    const _Float16* bstage;
    auto setB = [&](int phx) {
        const int dy = phx / 3 - 1;
        const int dx = phx - (phx / 3) * 3 - 1;
        const int y2 = py + dy, x2 = px + dx;
        const bool valid = ((unsigned)y2 < (unsigned)H) && ((unsigned)x2 < (unsigned)W);
        const int sp2 = (y2 << lgW) | x2;
        bstage = valid ? (in + ((size_t)((pb << lgHW) | sp2)) * CI + bh * 16)
                       : (zbuf + bh * 16);
    };

    f32x4v acc[4][4];
#pragma unroll
    for (int i = 0; i < 4; ++i)
#pragma unroll
        for (int j = 0; j < 4; ++j) acc[i][j] = (f32x4v)0.f;

    f16x8 aq[2][2], bq[2][2];
    int lph = 0, lcs = 0;
    setB(0);
    auto loadT = [&](int s) {
        const _Float16* ap = abase + (size_t)lph * CO * CI + (size_t)(cs0 + lcs) * 32;
        aq[s][0] = *(const f16x8*)ap;
        aq[s][1] = *(const f16x8*)(ap + 8);
        const _Float16* bp2 = bstage + (size_t)(cs0 + lcs) * 32;
        bq[s][0] = *(const f16x8*)bp2;
        bq[s][1] = *(const f16x8*)(bp2 + 8);
        if (++lcs == CS_PER) { lcs = 0; ++lph; if (lph < 9) setB(lph); }
    };
    loadT(0);        // tile 0
    loadT(1);        // tile 1
    // stage tile 0 -> buf 0
    *(f16x8*)&As[0][arow * 32 + aw0] = aq[0][0];
    *(f16x8*)&As[0][arow * 32 + aw1] = aq[0][1];
    *(f16x8*)&Bs[0][bn * 32 + bw0]   = bq[0][0];
    *(f16x8*)&Bs[0][bn * 32 + bw1]   = bq[0][1];

#pragma unroll 6
    for (int it = 0; it < NIT; ++it) {
        if (it + 2 < NIT) loadT(it & 1);          // tile it+2 into slot it%2
        if (it + 1 < NIT) {                       // stage tile it+1 -> buf (it+1)%3
            const int s1 = (it + 1) & 1;
            const int wb = (it + 1) % 3;
            *(f16x8*)&As[wb][arow * 32 + aw0] = aq[s1][0];
            *(f16x8*)&As[wb][arow * 32 + aw1] = aq[s1][1];
            *(f16x8*)&Bs[wb][bn * 32 + bw0]   = bq[s1][0];
            *(f16x8*)&Bs[wb][bn * 32 + bw1]   = bq[s1][1];
        }
        lds_barrier();
        const int rb = it % 3;
        f16x8 afr[4], bfr[4];
#pragma unroll
        for (int ti = 0; ti < 4; ++ti)
            afr[ti] = *(const f16x8*)&As[rb][(wm + ti * 16 + lm) * 32 + swz];
#pragma unroll
        for (int tj = 0; tj < 4; ++tj)
            bfr[tj] = *(const f16x8*)&Bs[rb][(wn + tj * 16 + lm) * 32 + swz];
#pragma unroll
        for (int ti = 0; ti < 4; ++ti)
#pragma unroll
            for (int tj = 0; tj < 4; ++tj)
                acc[ti][tj] = __builtin_amdgcn_mfma_f32_16x16x32_f16(
                    afr[ti], bfr[tj], acc[ti][tj], 0, 0, 0);
    }

    if (EPI == 2) {
        float* pout = part + (size_t)blockIdx.z * ((size_t)B * HW * CO);
#pragma unroll
        for (int tj = 0; tj < 4; ++tj) {
            const int gpix = pix0 + wn + tj * 16 + lm;
#pragma unroll
            for (int ti = 0; ti < 4; ++ti) {
                const int cob = co0 + wm + ti * 16 + q * 4;
                *(float4*)&pout[(size_t)gpix * CO + cob] =
                    make_float4(acc[ti][tj][0], acc[ti][tj][1],
                                acc[ti][tj][2], acc[ti][tj][3]);
            }
        }
    } else {
#pragma unroll
        for (int tj = 0; tj < 4; ++tj) {
            const int gpix = pix0 + wn + tj * 16 + lm;
#pragma unroll
            for (int ti = 0; ti < 4; ++ti) {
                const int cob = co0 + wm + ti * 16 + q * 4;
                f16x4 h4;
                if (EPI == 1) {
                    const float4 bb4 = *(const float4*)&bias[cob];
                    h4[0] = (_Float16)fmaxf(acc[ti][tj][0] + bb4.x, 0.f);
                    h4[1] = (_Float16)fmaxf(acc[ti][tj][1] + bb4.y, 0.f);
                    h4[2] = (_Float16)fmaxf(acc[ti][tj][2] + bb4.z, 0.f);
                    h4[3] = (_Float16)fmaxf(acc[ti][tj][3] + bb4.w, 0.f);
                } else {
#pragma unroll
                    for (int r = 0; r < 4; ++r) h4[r] = (_Float16)acc[ti][tj][r];
                }
                *(f16x4*)&out[(size_t)gpix * CO + cob] = h4;
            }
        }
    }
}

// ---------------- BN stats over NHWC f16 -----------------------------------
template <int C>
__global__ __launch_bounds__(256)
void bn_stats_nhwc_kernel(const _Float16* __restrict__ in, float* __restrict__ sums,
                          int Ptot)
{
    constexpr int C8 = C / 8;
    constexpr int PS = 256 / C8;
    const int chunk = Ptot / gridDim.x;
    const int c8   = threadIdx.x & (C8 - 1);
    const int poff = threadIdx.x >> ilog2c(C8);
    float s[8], s2[8];
#pragma unroll
    for (int j = 0; j < 8; ++j) { s[j] = 0.f; s2[j] = 0.f; }
    const int p0 = blockIdx.x * chunk;
    for (int p = p0 + poff; p < p0 + chunk; p += PS) {
        const f16x8 v = *(const f16x8*)(in + (size_t)p * C + c8 * 8);
#pragma unroll
        for (int j = 0; j < 8; ++j) {
            const float f = (float)v[j];
            s[j] += f; s2[j] += f * f;
        }
    }
    __shared__ float ls[2 * C];
    for (int i = threadIdx.x; i < 2 * C; i += 256) ls[i] = 0.f;
    __syncthreads();
#pragma unroll
    for (int j = 0; j < 8; ++j) {
        atomicAdd(&ls[c8 * 8 + j], s[j]);
        atomicAdd(&ls[C + c8 * 8 + j], s2[j]);
    }
    __syncthreads();
    for (int i = threadIdx.x; i < 2 * C; i += 256) atomicAdd(&sums[i], ls[i]);
}

template <int C>
__global__ void bn_finalize_kernel(const float* __restrict__ sums,
                                   const float* __restrict__ g,
                                   const float* __restrict__ beta,
                                   float* __restrict__ ss, int Ntot)
{
    const int c = blockIdx.x * 64 + threadIdx.x;
    if (c >= C) return;
    const float inv   = 1.f / (float)Ntot;
    const float mean  = sums[c] * inv;
    const float var   = sums[C + c] * inv - mean * mean;
    const float scale = g[c] * rsqrtf(var + BN_EPS);
    ss[c]     = scale;
    ss[C + c] = beta[c] - mean * scale;
}

// ---------------- maxpool k3 s2 p1, NHWC f16 (opt fused BN+ReLU) -----------
template <int C, int Hin, int Win, bool DO_BN>
__global__ __launch_bounds__(256)
void pool_nhwc_kernel(const _Float16* __restrict__ in, const float* __restrict__ ss,
                      _Float16* __restrict__ out, int B)
{
    constexpr int Ho = Hin / 2, Wo = Win / 2, C8 = C / 8;
    constexpr int lgC8 = ilog2c(C8), lgWo = ilog2c(Wo), lgHo = ilog2c(Ho);
    const int t = blockIdx.x * 256 + threadIdx.x;
    const int total = B * Ho * Wo * C8;
    if (t >= total) return;
    const int c8 = t & (C8 - 1);
    const int r1 = t >> lgC8;
    const int ox = r1 & (Wo - 1);
    const int r2 = r1 >> lgWo;
    const int oy = r2 & (Ho - 1);
    const int b  = r2 >> lgHo;

    float sc[8], sh[8];
    if (DO_BN) {
#pragma unroll
        for (int j = 0; j < 8; ++j) {
            sc[j] = ss[c8 * 8 + j];
            sh[j] = ss[C + c8 * 8 + j];
        }
    }
    float m[8];
#pragma unroll
    for (int j = 0; j < 8; ++j) m[j] = -1e30f;

    const int y0 = max(0, 2 * oy - 1), y1 = min(Hin - 1, 2 * oy + 1);
    const int x0 = max(0, 2 * ox - 1), x1 = min(Win - 1, 2 * ox + 1);
    const _Float16* ib = in + ((size_t)b * Hin * Win) * C + c8 * 8;
    for (int iy = y0; iy <= y1; ++iy)
        for (int ix = x0; ix <= x1; ++ix) {
            const f16x8 v = *(const f16x8*)(ib + (size_t)(iy * Win + ix) * C);
#pragma unroll
            for (int j = 0; j < 8; ++j) {
                float f = (float)v[j];
                if (DO_BN) f = f * sc[j] + sh[j];
                m[j] = fmaxf(m[j], f);
            }
        }
    f16x8 o;
#pragma unroll
    for (int j = 0; j < 8; ++j) {
        float f = m[j];
        if (DO_BN) f = fmaxf(f, 0.f);
        o[j] = (_Float16)f;
    }
    *(f16x8*)&out[((size_t)((b << (lgHo + lgWo)) | (oy << lgWo) | ox)) * C + c8 * 8] = o;
}

// ---------------- split-K partial reduce -> f16 NHWC -----------------------
template <int CO, int Z>
__global__ __launch_bounds__(256)
void sum_bias_relu_nhwc_kernel(const float* __restrict__ part, const float* __restrict__ bias,
                               _Float16* __restrict__ out, int Npix)
{
    const int t = blockIdx.x * 256 + threadIdx.x;
    const int N8 = Npix * CO / 8;
    if (t >= N8) return;
    const size_t i8 = (size_t)t * 8;
    const int c = (int)(i8 & (CO - 1));
    const size_t S = (size_t)Npix * CO;
    float4 x0 = *(const float4*)(part + i8);
    float4 x1 = *(const float4*)(part + i8 + 4);
#pragma unroll
    for (int z = 1; z < Z; ++z) {
        const float4 p0 = *(const float4*)(part + z * S + i8);
        const float4 p1 = *(const float4*)(part + z * S + i8 + 4);
        x0.x += p0.x; x0.y += p0.y; x0.z += p0.z; x0.w += p0.w;
        x1.x += p1.x; x1.y += p1.y; x1.z += p1.z; x1.w += p1.w;
    }
    const float4 b0 = *(const float4*)(bias + c);
    const float4 b1 = *(const float4*)(bias + c + 4);
    f16x8 o;
    o[0] = (_Float16)fmaxf(x0.x + b0.x, 0.f);
    o[1] = (_Float16)fmaxf(x0.y + b0.y, 0.f);
    o[2] = (_Float16)fmaxf(x0.z + b0.z, 0.f);
    o[3] = (_Float16)fmaxf(x0.w + b0.w, 0.f);
    o[4] = (_Float16)fmaxf(x1.x + b1.x, 0.f);
    o[5] = (_Float16)fmaxf(x1.y + b1.y, 0.f);
    o[6] = (_Float16)fmaxf(x1.z + b1.z, 0.f);
    o[7] = (_Float16)fmaxf(x1.w + b1.w, 0.f);
    *(f16x8*)&out[i8] = o;
}

// ---------------- conv7 partials -> X feats (f16) --------------------------
template <int Z>
__global__ __launch_bounds__(256)
void build_xf_kernel(const float* __restrict__ part, const float* __restrict__ bias,
                     _Float16* __restrict__ Xf, int B)
{
    const int t = blockIdx.x * 256 + threadIdx.x;
    if (t >= B * 16 * 128) return;
    const int pix = t >> 7;
    const int c   = (t & 127) * 4;
    const size_t S = (size_t)B * 16 * 512;
    float4 a = *(const float4*)(part + (size_t)pix * 512 + c);
#pragma unroll
    for (int z = 1; z < Z; ++z) {
        const float4 p = *(const float4*)(part + z * S + (size_t)pix * 512 + c);
        a.x += p.x; a.y += p.y; a.z += p.z; a.w += p.w;
    }
    const float4 bb = *(const float4*)(bias + c);
    f16x4 o4;
    o4[0] = (_Float16)fmaxf(a.x + bb.x, 0.f);
    o4[1] = (_Float16)fmaxf(a.y + bb.y, 0.f);
    o4[2] = (_Float16)fmaxf(a.z + bb.z, 0.f);
    o4[3] = (_Float16)fmaxf(a.w + bb.w, 0.f);
    const int b_ = pix >> 4, sp = pix & 15;
    *(f16x4*)&Xf[((size_t)(sp * B + b_)) * 512 + c] = o4;
}

// ---------------- fc1 MFMA: C[o][m] = W1T[o][k] . X[m][k] ------------------
template <int K, bool PASS2>
__global__ __launch_bounds__(256)
void fc1_mfma_kernel(const _Float16* __restrict__ Xf, const _Float16* __restrict__ W1T,
                     const float* __restrict__ b1p, float* __restrict__ pre,
                     float* __restrict__ h, int B)
{
    __shared__ __align__(16) _Float16 As[2][128 * 32];
    __shared__ __align__(16) _Float16 Bs[2][128 * 32];

    const int tid = threadIdx.x;
    const int o0  = blockIdx.x * 128;
    const int n   = blockIdx.y;

    const int lane = tid & 63, wv = tid >> 6;
    const int wm = (wv & 1) * 64, wn = (wv >> 1) * 64;
    const int q = lane >> 4, lm = lane & 15;
    const int swz = (q ^ (lm & 3)) << 3;

    const int arow = tid >> 1, ah = tid & 1;
    const int aw0 = ((2 * ah    ) ^ (arow & 3)) << 3;
    const int aw1 = ((2 * ah + 1) ^ (arow & 3)) << 3;

    const _Float16* asrc = W1T + ((size_t)(n * 640 + o0 + arow)) * K + ah * 16;
    const _Float16* bsrc = Xf  + ((size_t)(n * 128 + arow)) * K + ah * 16;

    f32x4v acc[4][4];
#pragma unroll
    for (int i = 0; i < 4; ++i)
#pragma unroll
        for (int j = 0; j < 4; ++j) acc[i][j] = (f32x4v)0.f;

    constexpr int S = K / 32;
    {
        const f16x8 a0 = *(const f16x8*)(asrc);
        const f16x8 a1 = *(const f16x8*)(asrc + 8);
        const f16x8 b0 = *(const f16x8*)(bsrc);
        const f16x8 b1 = *(const f16x8*)(bsrc + 8);
        *(f16x8*)&As[0][arow * 32 + aw0] = a0;
        *(f16x8*)&As[0][arow * 32 + aw1] = a1;
        *(f16x8*)&Bs[0][arow * 32 + aw0] = b0;
        *(f16x8*)&Bs[0][arow * 32 + aw1] = b1;
    }
    int buf = 0;
    for (int s = 0; s < S; ++s) {
        f16x8 aN0, aN1, bN0, bN1;
        if (s + 1 < S) {
            aN0 = *(const f16x8*)(asrc + (s + 1) * 32);
            aN1 = *(const f16x8*)(asrc + (s + 1) * 32 + 8);
            bN0 = *(const f16x8*)(bsrc + (s + 1) * 32);
            bN1 = *(const f16x8*)(bsrc + (s + 1) * 32 + 8);
        }
        lds_barrier();
        f16x8 afr[4], bfr[4];
#pragma unroll
        for (int ti = 0; ti < 4; ++ti)
            afr[ti] = *(const f16x8*)&As[buf][(wm + ti * 16 + lm) * 32 + swz];
#pragma unroll
        for (int tj = 0; tj < 4; ++tj)
            bfr[tj] = *(const f16x8*)&Bs[buf][(wn + tj * 16 + lm) * 32 + swz];
#pragma unroll
        for (int ti = 0; ti < 4; ++ti)
#pragma unroll
            for (int tj = 0; tj < 4; ++tj)
                acc[ti][tj] = __builtin_amdgcn_mfma_f32_16x16x32_f16(
                    afr[ti], bfr[tj], acc[ti][tj], 0, 0, 0);
        if (s + 1 < S) {
            *(f16x8*)&As[buf ^ 1][arow * 32 + aw0] = aN0;
            *(f16x8*)&As[buf ^ 1][arow * 32 + aw1] = aN1;
            *(f16x8*)&Bs[buf ^ 1][arow * 32 + aw0] = bN0;
            *(f16x8*)&Bs[buf ^ 1][arow * 32 + aw1] = bN1;
            buf ^= 1;
        }
    }

#pragma unroll
    for (int tj = 0; tj < 4; ++tj) {
        const int m = wn + tj * 16 + lm;
#pragma unroll
        for (int ti = 0; ti < 4; ++ti) {
            const int o = o0 + wm + ti * 16 + q * 4;
            const size_t oi = ((size_t)(n * 128 + m)) * 640 + o;
            float4 base;
            if (PASS2) base = *(const float4*)&pre[oi];
            else       base = *(const float4*)&b1p[n * 640 + o];
            float4 v = make_float4(acc[ti][tj][0] + base.x, acc[ti][tj][1] + base.y,
                                   acc[ti][tj][2] + base.z, acc[ti][tj][3] + base.w);
            if (!PASS2) *(float4*)&pre[oi] = v;
            *(float4*)&h[oi] = make_float4(tanhf(v.x), tanhf(v.y), tanhf(v.z), tanhf(v.w));
        }
    }
}

// ---------------- colons fc2 + softmax (h pitch 640) -----------------------
__global__ __launch_bounds__(128)
void colon_fc2_kernel(const float* __restrict__ h, const float* __restrict__ W2,
                      const float* __restrict__ b2, float* __restrict__ preds, int B)
{
    const int n = blockIdx.x;
    __shared__ float W2s[6000];
    __shared__ float b2s[10];
    for (int i = threadIdx.x; i < 6000; i += 128) W2s[i] = W2[n * 6000 + i];
    if (threadIdx.x < 10) b2s[threadIdx.x] = b2[n * 10 + threadIdx.x];
    __syncthreads();

    for (int b = threadIdx.x; b < B; b += 128) {
        float l[10];
#pragma unroll
        for (int c = 0; c < 10; ++c) l[c] = b2s[c];
        const float* hp = h + ((size_t)(n * B + b)) * 640;
        for (int k = 0; k < 600; k += 4) {
            const float4 hv = *reinterpret_cast<const float4*>(&hp[k]);
            const float hh[4] = {hv.x, hv.y, hv.z, hv.w};
#pragma unroll
            for (int u = 0; u < 4; ++u)
#pragma unroll
                for (int c = 0; c < 10; ++c)
                    l[c] += hh[u] * W2s[(k + u) * 10 + c];
        }
        float mx = l[0];
#pragma unroll
        for (int c = 1; c < 10; ++c) mx = fmaxf(mx, l[c]);
        float s = 0.f;
#pragma unroll
        for (int c = 0; c < 10; ++c) { l[c] = expf(l[c] - mx); s += l[c]; }
        const float inv = 1.f / s;
        float* pp = preds + ((size_t)(n * B + b)) * 10;
#pragma unroll
        for (int c = 0; c < 10; ++c) pp[c] = l[c] * inv;
    }
}

// ---------------- neighbor gather -> Xn f16 [16][B][96] --------------------
__global__ __launch_bounds__(256)
void fill_neigh_kernel(const float* __restrict__ preds1, _Float16* __restrict__ Xn, int B)
{
    const int t = blockIdx.x * 256 + threadIdx.x;
    if (t >= 16 * B * 96) return;
    const int col = t % 96;
    const int b   = (t / 96) % B;
    const int n   = t / (96 * B);

    float v = 0.f;
    if (col < 80) {
        const int j = col / 10, c = col - j * 10;
        int lst[8];
        int cnt = 0;
        const int w = 4, sz = 16, i = n;
        if (i - w >= 0)                                lst[cnt++] = i - w;
        if (i % w != 0)                                lst[cnt++] = i - 1;
        if ((i + 1) % w != 0)                          lst[cnt++] = i + 1;
        if (i + w < sz)                                lst[cnt++] = i + w;
        if (i - w - 1 >= 0 && i % w != 0)              lst[cnt++] = i - w - 1;
        if (i - w + 1 >= 0 && (i + 1) % w != 0)        lst[cnt++] = i - w + 1;
        if (i + w - 1 < sz && i % w != 0)              lst[cnt++] = i + w - 1;
        if (i + w + 1 < sz && (i + 1) % w != 0)        lst[cnt++] = i + w + 1;
        if (j < cnt) v = preds1[((size_t)(lst[j] * B + b)) * 10 + c];
    }
    Xn[t] = (_Float16)v;
}

// ---------------- final ----------------------------------------------------
__global__ __launch_bounds__(256)
void final_out_kernel(const float* __restrict__ preds2, float* __restrict__ out0, int B)
{
    const int t = blockIdx.x * 256 + threadIdx.x;
    if (t >= B * 10) return;
    const int b = t / 10, c = t % 10;
    float s = 0.f;
#pragma unroll
    for (int n = 0; n < 16; ++n)
        s += preds2[((size_t)(n * B + b)) * 10 + c];
    const float m = s * (1.f / 16.f);
    out0[t] = m * m;
}

// ---------------------------------------------------------------------------
extern "C" void kernel_launch(void* const* d_in, const int* in_sizes, int n_in,
                              void* d_out, int out_size, void* d_ws, size_t ws_size,
                              hipStream_t stream)
{
    const float* x    = (const float*)d_in[0];
    const float* cw1  = (const float*)d_in[1];
    const float* bn1g = (const float*)d_in[3];
    const float* bn1b = (const float*)d_in[4];
    const float* cw2  = (const float*)d_in[5];
    const float* bn2g = (const float*)d_in[7];
    const float* bn2b = (const float*)d_in[8];
    const float* cw3  = (const float*)d_in[9];
    const float* cb3  = (const float*)d_in[10];
    const float* cw4  = (const float*)d_in[11];
    const float* cb4  = (const float*)d_in[12];
    const float* cw5  = (const float*)d_in[13];
    const float* cb5  = (const float*)d_in[14];
    const float* cw6  = (const float*)d_in[15];
    const float* cb6  = (const float*)d_in[16];
    const float* cw7  = (const float*)d_in[17];
    const float* cb7  = (const float*)d_in[18];
    const float* W1   = (const float*)d_in[19];
    const float* b1   = (const float*)d_in[20];
    const float* W2   = (const float*)d_in[21];
    const float* b2   = (const float*)d_in[22];

    const int B = in_sizes[0] / (3 * 64 * 64);   // 128

    // ---- workspace layout (f32 offsets) ----
    float* ws = (float*)d_ws;
    float*     P    = ws;                                  // 8,388,608 f32
    _Float16*  A    = (_Float16*)(ws + 8388608);           // 33.6M f16
    _Float16*  Bb   = (_Float16*)(ws + 25165824);          // 16.8M f16
    _Float16*  wreg = (_Float16*)(ws + 33554432);          // conv weights f16
    _Float16*  W1Tf = (_Float16*)(ws + 36984832);          // 16*640*512 f16
    _Float16*  W1Tn = (_Float16*)(ws + 39606272);          // 16*640*96  f16
    _Float16*  Xf16 = (_Float16*)(ws + 40097792);          // 16*128*512 f16
    _Float16*  Xn16 = (_Float16*)(ws + 40622080);          // 16*128*96  f16
    float*     b1p  = ws + 40720384;                       // 16*640
    float*     preb = ws + 40730624;                       // 16*128*640
    float*     hb   = ws + 42041344;                       // 16*128*640
    float*     small= ws + 43352064;
    float* sums1  = small;          // 128
    float* sums2  = small + 256;    // 256
    float* ss1    = small + 1024;   // 128
    float* ss2    = small + 1536;   // 256
    float* preds1 = small + 2048;   // 16*B*10
    _Float16* zbuf = (_Float16*)(small + 32768);           // 4 KB zero page

    float* out0   = (float*)d_out;
    float* preds2 = (float*)d_out + (size_t)B * 10;

    hipMemsetAsync(small, 0, 512 * sizeof(float), stream);
    hipMemsetAsync(zbuf, 0, 4096, stream);

    // ---- weight pre-transforms (merged) ----
    wprep_kernel<<<dim3(1024, 7), 256, 0, stream>>>(cw1, cw2, cw3, cw4, cw5, cw6, cw7, wreg);
    w1t_kernel<<<dim3(10, 10, 16), 256, 0, stream>>>(W1, W1Tf, W1Tn);
    b1pad_kernel<<<(16 * 640 + 255) / 256, 256, 0, stream>>>(b1, b1p);

    _Float16* w1f  = wreg;
    _Float16* w9c2 = wreg + 2048;
    _Float16* w9c3 = wreg + 75776;
    _Float16* w9c4 = wreg + 370688;
    _Float16* w9c5 = wreg + 960512;
    _Float16* w9c6 = wreg + 2140160;
    _Float16* w9c7 = wreg + 4499456;

    // ---- backbone (acts f16 NHWC) ----
    conv1_mfma_kernel<<<B * 4096 / 128, 256, 0, stream>>>(x, w1f, A, B);
    bn_stats_nhwc_kernel<64><<<512, 256, 0, stream>>>(A, sums1, B * 4096);
    bn_finalize_kernel<64><<<1, 64, 0, stream>>>(sums1, bn1g, bn1b, ss1, B * 4096);
    pool_nhwc_kernel<64, 64, 64, true>
        <<<(B * 1024 * 8 + 255) / 256, 256, 0, stream>>>(A, ss1, Bb, B);

    conv_p2_kernel<64, 128, 32, 32, 1, 0>
        <<<dim3(B * 1024 / 128, 1), 256, 0, stream>>>(Bb, w9c2, nullptr, A, nullptr, zbuf, B);
    bn_stats_nhwc_kernel<128><<<256, 256, 0, stream>>>(A, sums2, B * 1024);
    bn_finalize_kernel<128><<<2, 64, 0, stream>>>(sums2, bn2g, bn2b, ss2, B * 1024);
    pool_nhwc_kernel<128, 32, 32, true>
        <<<(B * 256 * 16 + 255) / 256, 256, 0, stream>>>(A, ss2, Bb, B);

    conv_p2_kernel<128, 256, 16, 16, 1, 1>
        <<<dim3(B * 256 / 128, 2), 256, 0, stream>>>(Bb, w9c3, cb3, A, nullptr, zbuf, B);
    conv_p2_kernel<256, 256, 16, 16, 1, 1>
        <<<dim3(B * 256 / 128, 2), 256, 0, stream>>>(A, w9c4, cb4, Bb, nullptr, zbuf, B);
    pool_nhwc_kernel<256, 16, 16, false>
        <<<(B * 64 * 32 + 255) / 256, 256, 0, stream>>>(Bb, nullptr, A, B);

    conv_p2_kernel<256, 512, 8, 8, 2, 2>
        <<<dim3(B * 64 / 128, 4, 2), 256, 0, stream>>>(A, w9c5, nullptr, nullptr, P, zbuf, B);
    sum_bias_relu_nhwc_kernel<512, 2>
        <<<(B * 64 * 512 / 8 + 255) / 256, 256, 0, stream>>>(P, cb5, Bb, B * 64);

    conv_p2_kernel<512, 512, 8, 8, 2, 2>
        <<<dim3(B * 64 / 128, 4, 2), 256, 0, stream>>>(Bb, w9c6, nullptr, nullptr, P, zbuf, B);
    sum_bias_relu_nhwc_kernel<512, 2>
        <<<(B * 64 * 512 / 8 + 255) / 256, 256, 0, stream>>>(P, cb6, A, B * 64);
    pool_nhwc_kernel<512, 8, 8, false>
        <<<(B * 16 * 64 + 255) / 256, 256, 0, stream>>>(A, nullptr, Bb, B);

    conv_p2_kernel<512, 512, 4, 4, 8, 2>
        <<<dim3(B * 16 / 128, 4, 8), 256, 0, stream>>>(Bb, w9c7, nullptr, nullptr, P, zbuf, B);

    // ---- colons ----
    build_xf_kernel<8><<<(B * 16 * 128 + 255) / 256, 256, 0, stream>>>(P, cb7, Xf16, B);

    fc1_mfma_kernel<512, false>
        <<<dim3(5, 16), 256, 0, stream>>>(Xf16, W1Tf, b1p, preb, hb, B);
    colon_fc2_kernel<<<16, 128, 0, stream>>>(hb, W2, b2, preds1, B);

    fill_neigh_kernel<<<(16 * B * 96 + 255) / 256, 256, 0, stream>>>(preds1, Xn16, B);
    fc1_mfma_kernel<96, true>
        <<<dim3(5, 16), 256, 0, stream>>>(Xn16, W1Tn, b1p, preb, hb, B);
    colon_fc2_kernel<<<16, 128, 0, stream>>>(hb, W2, b2, preds2, B);

    final_out_kernel<<<(B * 10 + 255) / 256, 256, 0, stream>>>(preds2, out0, B);
}